// Round 1
// baseline (254.420 us; speedup 1.0000x reference)
//
#include <hip/hip_runtime.h>
#include <hip/hip_bf16.h>

#define DEVI static __device__ __forceinline__

typedef __attribute__((ext_vector_type(8))) short bf16x8;
typedef __attribute__((ext_vector_type(4))) float f32x4;
typedef __attribute__((ext_vector_type(4))) int i32x4;

constexpr int Bc = 4, Nc = 2048, Cc = 768, Hc = 12, Dhc = 64;
constexpr int Mc = Bc * Nc;   // 8192 tokens
constexpr int K3c = 3 * Cc;   // 2304

// fp32 -> bf16 round-to-nearest-even
DEVI unsigned int f2bf(float f) {
  unsigned int u = __float_as_uint(f);
  return (u + 0x7fffu + ((u >> 16) & 1u)) >> 16;
}
DEVI float bf2f(unsigned int u) { return __uint_as_float(u << 16); }

// ---------------------------------------------------------------------------
// GEMM: C[M,Nout] = A[M,K] * W[Nout,K]^T  (both row-major, K contiguous)
// AF32/WF32: input dtype fp32 (convert inline) vs bf16. OBF16: bf16 out vs fp32+bias.
// 128x128 tile, BK=64, 4 waves (2x2), mfma_f32_16x16x32_bf16.
// LDS tiles XOR-swizzled: 16B slot ^= (row&7)  -> conflict-free ds_read_b128.
// ---------------------------------------------------------------------------
template <int AF32, int WF32, int OBF16>
__global__ __launch_bounds__(256) void gemm_bt(const void* __restrict__ Ap,
                                               const void* __restrict__ Wp,
                                               void* __restrict__ Cp,
                                               const float* __restrict__ bias,
                                               int Mrows, int Nout, int Kdim) {
  __shared__ unsigned short As[128 * 64];
  __shared__ unsigned short Bs[128 * 64];
  const int tid = threadIdx.x;
  const int bn = blockIdx.x, bm = blockIdx.y;
  const int m0 = bm * 128, n0 = bn * 128;
  const int w = tid >> 6, lane = tid & 63;
  const int wr = w >> 1, wc = w & 1;
  const int lr = lane & 15, lg = lane >> 4;
  const int srow = tid >> 3, sslot = tid & 7;

  const f32x4 VZ = {0.f, 0.f, 0.f, 0.f};
  f32x4 acc[4][4];
#pragma unroll
  for (int i = 0; i < 4; ++i)
#pragma unroll
    for (int j = 0; j < 4; ++j) acc[i][j] = VZ;

  for (int kt = 0; kt < Kdim; kt += 64) {
    __syncthreads();
#pragma unroll
    for (int it = 0; it < 4; ++it) {
      const int row = it * 32 + srow;
      const int woff = row * 64 + ((sslot ^ (row & 7)) * 8);
      {
        const size_t off = (size_t)(m0 + row) * Kdim + kt + sslot * 8;
        i32x4 v;
        if constexpr (AF32) {
          const float* p = (const float*)Ap + off;
          v.x = (int)(f2bf(p[0]) | (f2bf(p[1]) << 16));
          v.y = (int)(f2bf(p[2]) | (f2bf(p[3]) << 16));
          v.z = (int)(f2bf(p[4]) | (f2bf(p[5]) << 16));
          v.w = (int)(f2bf(p[6]) | (f2bf(p[7]) << 16));
        } else {
          v = *(const i32x4*)((const unsigned short*)Ap + off);
        }
        *(i32x4*)&As[woff] = v;
      }
      {
        const size_t off = (size_t)(n0 + row) * Kdim + kt + sslot * 8;
        i32x4 v;
        if constexpr (WF32) {
          const float* p = (const float*)Wp + off;
          v.x = (int)(f2bf(p[0]) | (f2bf(p[1]) << 16));
          v.y = (int)(f2bf(p[2]) | (f2bf(p[3]) << 16));
          v.z = (int)(f2bf(p[4]) | (f2bf(p[5]) << 16));
          v.w = (int)(f2bf(p[6]) | (f2bf(p[7]) << 16));
        } else {
          v = *(const i32x4*)((const unsigned short*)Wp + off);
        }
        *(i32x4*)&Bs[woff] = v;
      }
    }
    __syncthreads();

    bf16x8 af[4][2], bfr[4][2];
#pragma unroll
    for (int mf = 0; mf < 4; ++mf) {
      const int row = wr * 64 + mf * 16 + lr;
#pragma unroll
      for (int kk = 0; kk < 2; ++kk)
        af[mf][kk] = *(const bf16x8*)&As[row * 64 + (((kk * 4 + lg) ^ (row & 7)) * 8)];
    }
#pragma unroll
    for (int nf = 0; nf < 4; ++nf) {
      const int row = wc * 64 + nf * 16 + lr;
#pragma unroll
      for (int kk = 0; kk < 2; ++kk)
        bfr[nf][kk] = *(const bf16x8*)&Bs[row * 64 + (((kk * 4 + lg) ^ (row & 7)) * 8)];
    }
#pragma unroll
    for (int mf = 0; mf < 4; ++mf)
#pragma unroll
      for (int nf = 0; nf < 4; ++nf)
#pragma unroll
        for (int kk = 0; kk < 2; ++kk)
          acc[mf][nf] = __builtin_amdgcn_mfma_f32_16x16x32_bf16(af[mf][kk], bfr[nf][kk],
                                                                acc[mf][nf], 0, 0, 0);
  }

  // epilogue: C/D layout col = lane&15, row = (lane>>4)*4 + reg
#pragma unroll
  for (int mf = 0; mf < 4; ++mf) {
#pragma unroll
    for (int nf = 0; nf < 4; ++nf) {
      const int col = n0 + wc * 64 + nf * 16 + lr;
#pragma unroll
      for (int r = 0; r < 4; ++r) {
        const int rowg = m0 + wr * 64 + mf * 16 + lg * 4 + r;
        const float v = acc[mf][nf][r];
        if constexpr (OBF16) {
          ((unsigned short*)Cp)[(size_t)rowg * Nout + col] = (unsigned short)f2bf(v);
        } else {
          ((float*)Cp)[(size_t)rowg * Nout + col] = v + bias[col];
        }
      }
    }
  }
}

// ---------------------------------------------------------------------------
// RoPE on q,k: qkv [B,N,3,H,Dh] bf16 -> Q,K [B,H,N,Dh] bf16
// ---------------------------------------------------------------------------
__global__ __launch_bounds__(256) void rope_qk(const unsigned short* __restrict__ qkv,
                                               const float* __restrict__ fcos,
                                               const float* __restrict__ fsin,
                                               unsigned short* __restrict__ Qo,
                                               unsigned short* __restrict__ Ko) {
  const int idx = blockIdx.x * 256 + threadIdx.x;
  if (idx >= Bc * Nc * Hc * 32) return;
  const int dp = idx & 31;
  const int t = idx >> 5;
  const int h = t % Hc;
  const int bn = t / Hc;
  const int n = bn & (Nc - 1);
  const int b = bn >> 11;
  const size_t qoff = (size_t)bn * 3 * Cc + h * 64 + dp * 2;
  const unsigned int qp = *(const unsigned int*)&qkv[qoff];
  const unsigned int kp = *(const unsigned int*)&qkv[qoff + Cc];
  const float c = fcos[n * 32 + dp], s = fsin[n * 32 + dp];
  const float qa = bf2f(qp & 0xffffu), qb = bf2f(qp >> 16);
  const float ka = bf2f(kp & 0xffffu), kb = bf2f(kp >> 16);
  const unsigned int qo = f2bf(qa * c - qb * s) | (f2bf(qa * s + qb * c) << 16);
  const unsigned int ko = f2bf(ka * c - kb * s) | (f2bf(ka * s + kb * c) << 16);
  const size_t o = ((size_t)((b * Hc + h) * Nc) + n) * Dhc + dp * 2;
  *(unsigned int*)&Qo[o] = qo;
  *(unsigned int*)&Ko[o] = ko;
}

// ---------------------------------------------------------------------------
// V transpose: qkv v-slice [B,N,H,Dh] -> Vt [B,H,Dh,N]
// ---------------------------------------------------------------------------
__global__ __launch_bounds__(256) void vtrans(const unsigned short* __restrict__ qkv,
                                              unsigned short* __restrict__ Vt) {
  __shared__ unsigned short tile[64 * 72];  // pad rows to 72 elems
  const int nt = blockIdx.x, bh = blockIdx.y;
  const int b = bh / Hc, h = bh % Hc;
  const int tid = threadIdx.x;
  const int n0 = nt * 64;
  const int rrow = tid >> 3, rslot = tid & 7;
#pragma unroll
  for (int it = 0; it < 2; ++it) {
    const int n = it * 32 + rrow;
    i32x4 v = *(const i32x4*)&qkv[((size_t)(b * Nc + n0 + n) * 3 + 2) * Cc + h * 64 + rslot * 8];
    *(i32x4*)&tile[n * 72 + rslot * 8] = v;
  }
  __syncthreads();
#pragma unroll
  for (int it = 0; it < 2; ++it) {
    const int task = it * 256 + tid;
    const int d = task >> 3, ns = task & 7;
    unsigned short tmp[8];
#pragma unroll
    for (int j = 0; j < 8; ++j) tmp[j] = tile[(ns * 8 + j) * 72 + d];
    *(i32x4*)&Vt[((size_t)(bh * Dhc + d)) * Nc + n0 + ns * 8] = *(const i32x4*)tmp;
  }
}

// ---------------------------------------------------------------------------
// Causal flash attention. Block = 4 waves, 64 q-rows (16 per wave), KV tile 64.
// Swapped QK^T: S^T = mfma(K_frag, Q_frag) so each lane owns one q column.
// P goes through per-wave swizzled LDS to become the PV B-operand.
// O^T = mfma(Vt_frag, P_frag). Output [B,N,H*Dh] bf16.
// ---------------------------------------------------------------------------
__global__ __launch_bounds__(256) void attn_fwd(const unsigned short* __restrict__ Qp,
                                                const unsigned short* __restrict__ Kp,
                                                const unsigned short* __restrict__ Vtp,
                                                unsigned short* __restrict__ Op) {
  __shared__ unsigned short Ks[64 * 64];
  __shared__ unsigned short Vs[64 * 64];
  __shared__ unsigned short Ps[4][16 * 64];
  const int qt = blockIdx.x, bh = blockIdx.y;
  const int tid = threadIdx.x, w = tid >> 6, lane = tid & 63;
  const int lr = lane & 15, lg = lane >> 4;
  const int q0 = qt * 64;
  const int qrow = q0 + w * 16 + lr;  // this lane's q index
  const int srow = tid >> 3, sslot = tid & 7;
  const float scale = 0.125f;  // 1/sqrt(64)

  bf16x8 qf[2];
  {
    const size_t qb = ((size_t)bh * Nc + qrow) * Dhc;
    qf[0] = *(const bf16x8*)&Qp[qb + lg * 8];
    qf[1] = *(const bf16x8*)&Qp[qb + 32 + lg * 8];
  }
  const f32x4 VZ = {0.f, 0.f, 0.f, 0.f};
  f32x4 oacc[4];
#pragma unroll
  for (int f = 0; f < 4; ++f) oacc[f] = VZ;
  float m_run = -1e30f, l_run = 0.f;

  for (int k0 = 0; k0 <= q0; k0 += 64) {
    __syncthreads();
#pragma unroll
    for (int it = 0; it < 2; ++it) {
      const int row = it * 32 + srow;
      const int woff = row * 64 + ((sslot ^ (row & 7)) * 8);
      i32x4 kv = *(const i32x4*)&Kp[((size_t)bh * Nc + k0 + row) * Dhc + sslot * 8];
      *(i32x4*)&Ks[woff] = kv;
      i32x4 vv = *(const i32x4*)&Vtp[((size_t)bh * Dhc + row) * Nc + k0 + sslot * 8];
      *(i32x4*)&Vs[woff] = vv;
    }
    __syncthreads();

    // S^T tile: rows = kv (4 frags), cols = q
    f32x4 sacc[4];
#pragma unroll
    for (int f = 0; f < 4; ++f) {
      sacc[f] = VZ;
#pragma unroll
      for (int kk = 0; kk < 2; ++kk) {
        const int row = f * 16 + lr;
        bf16x8 kf = *(const bf16x8*)&Ks[row * 64 + (((kk * 4 + lg) ^ (row & 7)) * 8)];
        sacc[f] = __builtin_amdgcn_mfma_f32_16x16x32_bf16(kf, qf[kk], sacc[f], 0, 0, 0);
      }
    }

    // scale + causal mask + online softmax (per-lane q fixed)
    float sv[4][4];
    float pmax = -1e30f;
#pragma unroll
    for (int f = 0; f < 4; ++f)
#pragma unroll
      for (int r = 0; r < 4; ++r) {
        const int kvi = k0 + f * 16 + lg * 4 + r;
        float v = sacc[f][r] * scale;
        v = (kvi <= qrow) ? v : -1e30f;
        sv[f][r] = v;
        pmax = fmaxf(pmax, v);
      }
    pmax = fmaxf(pmax, __shfl_xor(pmax, 16, 64));
    pmax = fmaxf(pmax, __shfl_xor(pmax, 32, 64));
    const float m_new = fmaxf(m_run, pmax);
    const float resc = __expf(m_run - m_new);
    m_run = m_new;

    float psum = 0.f;
    unsigned long long pw[4];
#pragma unroll
    for (int f = 0; f < 4; ++f) {
      const float p0 = __expf(sv[f][0] - m_new);
      const float p1 = __expf(sv[f][1] - m_new);
      const float p2 = __expf(sv[f][2] - m_new);
      const float p3 = __expf(sv[f][3] - m_new);
      psum += (p0 + p1) + (p2 + p3);
      const unsigned int lo = f2bf(p0) | (f2bf(p1) << 16);
      const unsigned int hi = f2bf(p2) | (f2bf(p3) << 16);
      pw[f] = ((unsigned long long)hi << 32) | lo;
    }
    psum += __shfl_xor(psum, 16, 64);
    psum += __shfl_xor(psum, 32, 64);
    l_run = l_run * resc + psum;
#pragma unroll
    for (int f = 0; f < 4; ++f) {
      oacc[f][0] *= resc; oacc[f][1] *= resc; oacc[f][2] *= resc; oacc[f][3] *= resc;
    }

    // P^T -> per-wave LDS (layout [q][kv], swizzled)
    char* pbase = (char*)&Ps[w][0] + lr * 128;
#pragma unroll
    for (int f = 0; f < 4; ++f)
      *(unsigned long long*)(pbase + ((f * 32 + lg * 8) ^ ((lr & 7) << 4))) = pw[f];

    // O^T += Vt_frag * P_frag
#pragma unroll
    for (int f = 0; f < 4; ++f)
#pragma unroll
      for (int kk = 0; kk < 2; ++kk) {
        const int row = f * 16 + lr;
        bf16x8 vf = *(const bf16x8*)&Vs[row * 64 + (((kk * 4 + lg) ^ (row & 7)) * 8)];
        bf16x8 pf = *(const bf16x8*)(pbase + (((kk * 4 + lg) * 16) ^ ((lr & 7) << 4)));
        oacc[f] = __builtin_amdgcn_mfma_f32_16x16x32_bf16(vf, pf, oacc[f], 0, 0, 0);
      }
  }

  const float inv = 1.f / l_run;
  const int b = bh / Hc, h = bh % Hc;
#pragma unroll
  for (int f = 0; f < 4; ++f) {
    const unsigned int w0 = f2bf(oacc[f][0] * inv) | (f2bf(oacc[f][1] * inv) << 16);
    const unsigned int w1 = f2bf(oacc[f][2] * inv) | (f2bf(oacc[f][3] * inv) << 16);
    const size_t off = ((size_t)(b * Nc + qrow)) * Cc + h * 64 + f * 16 + lg * 4;
    uint2 val;
    val.x = w0;
    val.y = w1;
    *(uint2*)&Op[off] = val;
  }
}

// ---------------------------------------------------------------------------
// Workspace layout (bytes):
//   qkv bf16 [8192,2304] : 37,748,736   (reused for attn output later)
//   Q   bf16 [48,2048,64]: 12,582,912
//   K   bf16 [48,2048,64]: 12,582,912
//   Vt  bf16 [48,64,2048]: 12,582,912
// total 75,497,472
// ---------------------------------------------------------------------------
extern "C" void kernel_launch(void* const* d_in, const int* in_sizes, int n_in,
                              void* d_out, int out_size, void* d_ws, size_t ws_size,
                              hipStream_t stream) {
  const float* x = (const float*)d_in[0];
  const float* fcos = (const float*)d_in[1];
  const float* fsin = (const float*)d_in[2];
  // d_in[3] (mask) unused: causal structure applied analytically
  const float* wqkv = (const float*)d_in[4];
  const float* wproj = (const float*)d_in[5];
  const float* bproj = (const float*)d_in[6];

  char* ws = (char*)d_ws;
  unsigned short* qkvb = (unsigned short*)(ws);
  unsigned short* Qb = (unsigned short*)(ws + 37748736);
  unsigned short* Kb = (unsigned short*)(ws + 37748736 + 12582912);
  unsigned short* Vtb = (unsigned short*)(ws + 37748736 + 2 * 12582912);
  unsigned short* attnb = qkvb;  // reuse (qkv dead after rope+vtrans)

  // 1. qkv = x @ w_qkv^T   (fp32 in, bf16 out)
  gemm_bt<1, 1, 1><<<dim3(K3c / 128, Mc / 128), 256, 0, stream>>>(x, wqkv, qkvb, nullptr,
                                                                  Mc, K3c, Cc);
  // 2. RoPE -> Q,K [B,H,N,Dh]
  rope_qk<<<dim3(Bc * Nc * Hc * 32 / 256), 256, 0, stream>>>(qkvb, fcos, fsin, Qb, Kb);
  // 3. V transpose -> Vt [B,H,Dh,N]
  vtrans<<<dim3(Nc / 64, Bc * Hc), 256, 0, stream>>>(qkvb, Vtb);
  // 4. causal attention -> attnb [B,N,C] bf16
  attn_fwd<<<dim3(Nc / 64, Bc * Hc), 256, 0, stream>>>(Qb, Kb, Vtb, attnb);
  // 5. out = attn @ w_proj^T + b  (fp32 out)
  gemm_bt<0, 1, 0><<<dim3(Cc / 128, Mc / 128), 256, 0, stream>>>(attnb, wproj, d_out, bproj,
                                                                 Mc, Cc, Cc);
}

// Round 3
// 220.797 us; speedup vs baseline: 1.1523x; 1.1523x over previous
//
#include <hip/hip_runtime.h>
#include <hip/hip_bf16.h>

#define DEVI static __device__ __forceinline__

typedef __attribute__((ext_vector_type(8))) short bf16x8;
typedef __attribute__((ext_vector_type(4))) float f32x4;
typedef __attribute__((ext_vector_type(16))) float f32x16;
typedef __attribute__((ext_vector_type(4))) int i32x4;

constexpr int Bc = 4, Nc = 2048, Cc = 768, Hc = 12, Dhc = 64;
constexpr int Mc = Bc * Nc;   // 8192 tokens
constexpr int K3c = 3 * Cc;   // 2304

// fp32 -> bf16 round-to-nearest-even
DEVI unsigned int f2bf(float f) {
  unsigned int u = __float_as_uint(f);
  return (u + 0x7fffu + ((u >> 16) & 1u)) >> 16;
}
DEVI float bf2f(unsigned int u) { return __uint_as_float(u << 16); }

DEVI unsigned int cvtpk_bf16(float lo, float hi_) {
  unsigned int r;
  asm("v_cvt_pk_bf16_f32 %0, %1, %2" : "=v"(r) : "v"(lo), "v"(hi_));
  return r;
}

#define GLOAD_LDS(g, l)                                                              \
  __builtin_amdgcn_global_load_lds((const __attribute__((address_space(1))) void*)(g), \
                                   (__attribute__((address_space(3))) void*)(l), 16, 0, 0)

// ---------------------------------------------------------------------------
// fp32 -> bf16 bulk convert, 8 elems/thread
// ---------------------------------------------------------------------------
__global__ __launch_bounds__(256) void cvt_f32_bf16(const float* __restrict__ in,
                                                    unsigned short* __restrict__ out, int n8) {
  const int i = blockIdx.x * 256 + threadIdx.x;
  if (i >= n8) return;
  const f32x4 a = *((const f32x4*)in + (size_t)i * 2);
  const f32x4 b = *((const f32x4*)in + (size_t)i * 2 + 1);
  i32x4 v;
  v.x = (int)(f2bf(a.x) | (f2bf(a.y) << 16));
  v.y = (int)(f2bf(a.z) | (f2bf(a.w) << 16));
  v.z = (int)(f2bf(b.x) | (f2bf(b.y) << 16));
  v.w = (int)(f2bf(b.z) | (f2bf(b.w) << 16));
  *((i32x4*)out + i) = v;
}

// ---------------------------------------------------------------------------
// GEMM: C[M,Nout] = A[M,K] * W[Nout,K]^T, bf16 in. 128x128 tile, BK=64,
// 4 waves (2x2), mfma 16x16x32. Staging via global_load_lds (width 16),
// pre-swizzled global source (slot ^= row&7) + linear LDS + swizzled reads.
// ---------------------------------------------------------------------------
template <int OBF16>
__global__ __launch_bounds__(256) void gemm_bt16(const unsigned short* __restrict__ Ap,
                                                 const unsigned short* __restrict__ Wp,
                                                 void* __restrict__ Cp,
                                                 const float* __restrict__ bias,
                                                 int Nout, int Kdim) {
  __shared__ unsigned short As[128 * 64];
  __shared__ unsigned short Bs[128 * 64];
  const int tid = threadIdx.x;
  const int bn = blockIdx.x, bm = blockIdx.y;
  const int m0 = bm * 128, n0 = bn * 128;
  const int w = tid >> 6, lane = tid & 63;
  const int wr = w >> 1, wc = w & 1;
  const int lr = lane & 15, lg = lane >> 4;
  const int r = lane >> 3, slot = lane & 7;

  f32x4 acc[4][4];
#pragma unroll
  for (int i = 0; i < 4; ++i)
#pragma unroll
    for (int j = 0; j < 4; ++j) acc[i][j] = f32x4{0.f, 0.f, 0.f, 0.f};

  for (int kt = 0; kt < Kdim; kt += 64) {
    __syncthreads();
#pragma unroll
    for (int c = 0; c < 4; ++c) {
      const int i = (w << 2) + c;
      const int row = (i << 3) + r;
      const unsigned short* ga = Ap + (size_t)(m0 + row) * Kdim + kt + ((slot ^ r) << 3);
      GLOAD_LDS(ga, As + (i << 9));
      const unsigned short* gb = Wp + (size_t)(n0 + row) * Kdim + kt + ((slot ^ r) << 3);
      GLOAD_LDS(gb, Bs + (i << 9));
    }
    __syncthreads();

    bf16x8 af[4][2], bfr[4][2];
#pragma unroll
    for (int mf = 0; mf < 4; ++mf) {
      const int row = wr * 64 + mf * 16 + lr;
#pragma unroll
      for (int kk = 0; kk < 2; ++kk)
        af[mf][kk] = *(const bf16x8*)&As[row * 64 + (((kk * 4 + lg) ^ (row & 7)) * 8)];
    }
#pragma unroll
    for (int nf = 0; nf < 4; ++nf) {
      const int row = wc * 64 + nf * 16 + lr;
#pragma unroll
      for (int kk = 0; kk < 2; ++kk)
        bfr[nf][kk] = *(const bf16x8*)&Bs[row * 64 + (((kk * 4 + lg) ^ (row & 7)) * 8)];
    }
#pragma unroll
    for (int mf = 0; mf < 4; ++mf)
#pragma unroll
      for (int nf = 0; nf < 4; ++nf)
#pragma unroll
        for (int kk = 0; kk < 2; ++kk)
          acc[mf][nf] = __builtin_amdgcn_mfma_f32_16x16x32_bf16(af[mf][kk], bfr[nf][kk],
                                                                acc[mf][nf], 0, 0, 0);
  }

#pragma unroll
  for (int mf = 0; mf < 4; ++mf) {
#pragma unroll
    for (int nf = 0; nf < 4; ++nf) {
      const int col = n0 + wc * 64 + nf * 16 + lr;
#pragma unroll
      for (int rg = 0; rg < 4; ++rg) {
        const int rowg = m0 + wr * 64 + mf * 16 + lg * 4 + rg;
        const float v = acc[mf][nf][rg];
        if constexpr (OBF16) {
          ((unsigned short*)Cp)[(size_t)rowg * Nout + col] = (unsigned short)f2bf(v);
        } else {
          ((float*)Cp)[(size_t)rowg * Nout + col] = v + bias[col];
        }
      }
    }
  }
}

// ---------------------------------------------------------------------------
// RoPE on q,k: qkv [B,N,3,H,Dh] bf16 -> Q,K [B,H,N,Dh] bf16
// ---------------------------------------------------------------------------
__global__ __launch_bounds__(256) void rope_qk(const unsigned short* __restrict__ qkv,
                                               const float* __restrict__ fcos,
                                               const float* __restrict__ fsin,
                                               unsigned short* __restrict__ Qo,
                                               unsigned short* __restrict__ Ko) {
  const int idx = blockIdx.x * 256 + threadIdx.x;
  if (idx >= Bc * Nc * Hc * 32) return;
  const int dp = idx & 31;
  const int t = idx >> 5;
  const int h = t % Hc;
  const int bn = t / Hc;
  const int n = bn & (Nc - 1);
  const int b = bn >> 11;
  const size_t qoff = (size_t)bn * 3 * Cc + h * 64 + dp * 2;
  const unsigned int qp = *(const unsigned int*)&qkv[qoff];
  const unsigned int kp = *(const unsigned int*)&qkv[qoff + Cc];
  const float c = fcos[n * 32 + dp], s = fsin[n * 32 + dp];
  const float qa = bf2f(qp & 0xffffu), qb = bf2f(qp >> 16);
  const float ka = bf2f(kp & 0xffffu), kb = bf2f(kp >> 16);
  const unsigned int qo = f2bf(qa * c - qb * s) | (f2bf(qa * s + qb * c) << 16);
  const unsigned int ko = f2bf(ka * c - kb * s) | (f2bf(ka * s + kb * c) << 16);
  const size_t o = ((size_t)((b * Hc + h) * Nc) + n) * Dhc + dp * 2;
  *(unsigned int*)&Qo[o] = qo;
  *(unsigned int*)&Ko[o] = ko;
}

// ---------------------------------------------------------------------------
// V transpose: qkv v-slice [B,N,H,Dh] -> Vt [B,H,Dh,N]
// ---------------------------------------------------------------------------
__global__ __launch_bounds__(256) void vtrans(const unsigned short* __restrict__ qkv,
                                              unsigned short* __restrict__ Vt) {
  __shared__ unsigned short tile[64 * 72];
  const int nt = blockIdx.x, bh = blockIdx.y;
  const int b = bh / Hc, h = bh % Hc;
  const int tid = threadIdx.x;
  const int n0 = nt * 64;
  const int rrow = tid >> 3, rslot = tid & 7;
#pragma unroll
  for (int it = 0; it < 2; ++it) {
    const int n = it * 32 + rrow;
    i32x4 v = *(const i32x4*)&qkv[((size_t)(b * Nc + n0 + n) * 3 + 2) * Cc + h * 64 + rslot * 8];
    *(i32x4*)&tile[n * 72 + rslot * 8] = v;
  }
  __syncthreads();
#pragma unroll
  for (int it = 0; it < 2; ++it) {
    const int task = it * 256 + tid;
    const int d = task >> 3, ns = task & 7;
    unsigned short tmp[8];
#pragma unroll
    for (int j = 0; j < 8; ++j) tmp[j] = tile[(ns * 8 + j) * 72 + d];
    *(i32x4*)&Vt[((size_t)(bh * Dhc + d)) * Nc + n0 + ns * 8] = *(const i32x4*)tmp;
  }
}

// ---------------------------------------------------------------------------
// Causal flash attention, 4 waves x 32 q-rows = 128 q/block, KV tile 64,
// mfma 32x32x16. Swapped QK^T (S^T = mfma(K,Q)): lane owns one q column.
// In-register softmax (exp2 domain, defer-max THR=11.5), P->bf16 via
// cvt_pk + permlane32_swap (no LDS). permlane32_swap semantics:
// vdst[32:63] <-> vsrc[0:31], so the EARLIER-kv word is vdst:
// swap(w0,w2): w0 -> kv hi*8+{0,1}, w2 -> kv hi*8+{4,5}.  (Round-1 bug:
// operands were reversed, scrambling the PV B-fragment.)
// PV: O^T = mfma(Vt, P). K/V double-buffered in LDS via global_load_lds,
// XOR-swizzle via pre-swizzled source. Output [B,N,H*Dh] bf16.
// ---------------------------------------------------------------------------
__global__ __launch_bounds__(256) void attn_fwd(const unsigned short* __restrict__ Qp,
                                                const unsigned short* __restrict__ Kp,
                                                const unsigned short* __restrict__ Vtp,
                                                unsigned short* __restrict__ Op) {
  __shared__ unsigned short lds[2][2][4096];  // [buf][K/V][64*64]
  const int qtile = (int)gridDim.x - 1 - (int)blockIdx.x;  // heavy tiles first
  const int bh = blockIdx.y;
  const int q0 = qtile * 128;
  const int tid = threadIdx.x, w = tid >> 6, lane = tid & 63;
  const int qc = lane & 31, hi = lane >> 5;
  const int qrow = q0 + w * 32 + qc;
  const int qwmax = q0 + w * 32 + 31;
  const int r = lane >> 3, slot = lane & 7;
  const unsigned short* Kb = Kp + (size_t)bh * (Nc * 64);
  const unsigned short* Vb = Vtp + (size_t)bh * (64 * Nc);

  bf16x8 qf[4];
  {
    const unsigned short* qptr = Qp + ((size_t)bh * Nc + qrow) * 64 + hi * 8;
#pragma unroll
    for (int ks = 0; ks < 4; ++ks) qf[ks] = *(const bf16x8*)(qptr + ks * 16);
  }

  f32x16 oacc[2];
#pragma unroll
  for (int dt = 0; dt < 2; ++dt)
#pragma unroll
    for (int j = 0; j < 16; ++j) oacc[dt][j] = 0.f;
  float m_run = -1e30f, l_run = 0.f;
  constexpr float KL = 0.18033688011112042f;  // (1/sqrt(64)) * log2(e)

  const int nt = qtile * 2 + 2;

  auto stage = [&](int b_, int k0s) {
#pragma unroll
    for (int c = 0; c < 2; ++c) {
      const int i = w * 2 + c;
      const int row = i * 8 + r;
      const unsigned short* gk = Kb + (size_t)(k0s + row) * 64 + ((slot ^ r) << 3);
      GLOAD_LDS(gk, &lds[b_][0][0] + i * 512);
      const unsigned short* gv = Vb + (size_t)row * Nc + k0s + ((slot ^ r) << 3);
      GLOAD_LDS(gv, &lds[b_][1][0] + i * 512);
    }
  };

  stage(0, 0);
  int cur = 0;
  for (int t = 0; t < nt; ++t) {
    __syncthreads();
    if (t + 1 < nt) stage(cur ^ 1, (t + 1) * 64);
    const int k0 = t * 64;
    if (k0 <= qwmax) {  // skip fully-masked diagonal tiles for low waves
      const unsigned short* Ks = &lds[cur][0][0];
      const unsigned short* Vs = &lds[cur][1][0];

      // --- QK^T : S^T[kv][q]
      f32x16 sacc[2];
#pragma unroll
      for (int f = 0; f < 2; ++f)
#pragma unroll
        for (int j = 0; j < 16; ++j) sacc[f][j] = 0.f;
#pragma unroll
      for (int f = 0; f < 2; ++f) {
        const int krow = f * 32 + qc;
        const char* kbase = (const char*)Ks + krow * 128;
        const int sw = krow & 7;
#pragma unroll
        for (int ks = 0; ks < 4; ++ks) {
          bf16x8 kf = *(const bf16x8*)(kbase + (((ks * 2 + hi) ^ sw) << 4));
          sacc[f] = __builtin_amdgcn_mfma_f32_32x32x16_bf16(kf, qf[ks], sacc[f], 0, 0, 0);
        }
      }

      // --- online softmax (exp2 domain); lane kv rows: (rr&3)+8*(rr>>2)+4*hi
      const bool masked = (t >= nt - 2);
      float pmax = -1e30f;
#pragma unroll
      for (int f = 0; f < 2; ++f)
#pragma unroll
        for (int rr = 0; rr < 16; ++rr) {
          float v = sacc[f][rr] * KL;
          if (masked) {
            const int kvi = k0 + f * 32 + (rr & 3) + ((rr >> 2) << 3) + (hi << 2);
            v = (kvi <= qrow) ? v : -1e30f;
          }
          pmax = fmaxf(pmax, v);
        }
      pmax = fmaxf(pmax, __shfl_xor(pmax, 32, 64));
      if (!__all(pmax - m_run <= 11.5f)) {  // defer-max (T13)
        const float m_new = fmaxf(m_run, pmax);
        const float rs = exp2f(m_run - m_new);
        l_run *= rs;
#pragma unroll
        for (int dt = 0; dt < 2; ++dt)
#pragma unroll
          for (int j = 0; j < 16; ++j) oacc[dt][j] *= rs;
        m_run = m_new;
      }

      float psum = 0.f;
      unsigned int pw[2][8];
#pragma unroll
      for (int f = 0; f < 2; ++f) {
        float p[16];
#pragma unroll
        for (int rr = 0; rr < 16; ++rr) {
          float p_ = exp2f(fmaf(sacc[f][rr], KL, -m_run));
          if (masked) {
            const int kvi = k0 + f * 32 + (rr & 3) + ((rr >> 2) << 3) + (hi << 2);
            p_ = (kvi <= qrow) ? p_ : 0.f;
          }
          p[rr] = p_;
          psum += p_;
        }
#pragma unroll
        for (int j = 0; j < 8; ++j) pw[f][j] = cvtpk_bf16(p[2 * j], p[2 * j + 1]);
        // T12: earlier-kv word is vdst (vdst[32:63] <-> vsrc[0:31])
        asm volatile("v_permlane32_swap_b32 %0, %1" : "+v"(pw[f][0]), "+v"(pw[f][2]));
        asm volatile("v_permlane32_swap_b32 %0, %1" : "+v"(pw[f][1]), "+v"(pw[f][3]));
        asm volatile("v_permlane32_swap_b32 %0, %1" : "+v"(pw[f][4]), "+v"(pw[f][6]));
        asm volatile("v_permlane32_swap_b32 %0, %1" : "+v"(pw[f][5]), "+v"(pw[f][7]));
      }
      psum += __shfl_xor(psum, 32, 64);
      l_run += psum;

      // --- PV: O^T[d][q] += V^T x P
#pragma unroll
      for (int dt = 0; dt < 2; ++dt) {
        const int vrow = dt * 32 + qc;
        const char* vbase = (const char*)Vs + vrow * 128;
        const int swv = vrow & 7;
#pragma unroll
        for (int ks = 0; ks < 4; ++ks) {
          bf16x8 vf = *(const bf16x8*)(vbase + (((ks * 2 + hi) ^ swv) << 4));
          i32x4 pi;
          pi.x = (int)pw[ks >> 1][(ks & 1) * 4 + 0];
          pi.y = (int)pw[ks >> 1][(ks & 1) * 4 + 1];
          pi.z = (int)pw[ks >> 1][(ks & 1) * 4 + 2];
          pi.w = (int)pw[ks >> 1][(ks & 1) * 4 + 3];
          bf16x8 pf = __builtin_bit_cast(bf16x8, pi);
          oacc[dt] = __builtin_amdgcn_mfma_f32_32x32x16_bf16(vf, pf, oacc[dt], 0, 0, 0);
        }
      }
    }
    cur ^= 1;
  }

  // --- epilogue: lane owns q column; d = dt*32 + rq*8 + hi*4 + (0..3)
  const float inv = 1.f / l_run;
  const int b = bh / Hc, h = bh % Hc;
  unsigned short* orow = Op + ((size_t)(b * Nc + qrow)) * Cc + h * 64;
#pragma unroll
  for (int dt = 0; dt < 2; ++dt)
#pragma unroll
    for (int rq = 0; rq < 4; ++rq) {
      const float o0 = oacc[dt][rq * 4 + 0] * inv;
      const float o1 = oacc[dt][rq * 4 + 1] * inv;
      const float o2 = oacc[dt][rq * 4 + 2] * inv;
      const float o3 = oacc[dt][rq * 4 + 3] * inv;
      uint2 val;
      val.x = f2bf(o0) | (f2bf(o1) << 16);
      val.y = f2bf(o2) | (f2bf(o3) << 16);
      *(uint2*)(orow + dt * 32 + rq * 8 + hi * 4) = val;
    }
}

// ---------------------------------------------------------------------------
// Workspace layout (75,497,472 B total):
//   [0,       37.75M) qkv bf16          (later reused as attn output)
//   [37.75M, +12.58M) x_bf16, then Q    (x dead before rope writes Q)
//   [50.33M, +12.58M) wqkv_bf16, then K (dead before rope writes K)
//   [62.91M, +12.58M) Vt, then wproj_bf16 after attn consumes Vt
// ---------------------------------------------------------------------------
extern "C" void kernel_launch(void* const* d_in, const int* in_sizes, int n_in,
                              void* d_out, int out_size, void* d_ws, size_t ws_size,
                              hipStream_t stream) {
  const float* x = (const float*)d_in[0];
  const float* fcos = (const float*)d_in[1];
  const float* fsin = (const float*)d_in[2];
  // d_in[3] (mask) unused: causal structure applied analytically
  const float* wqkv = (const float*)d_in[4];
  const float* wproj = (const float*)d_in[5];
  const float* bproj = (const float*)d_in[6];

  char* ws = (char*)d_ws;
  unsigned short* qkvb = (unsigned short*)ws;
  unsigned short* Qb = (unsigned short*)(ws + 37748736);
  unsigned short* Kbuf = (unsigned short*)(ws + 37748736 + 12582912);
  unsigned short* Vtb = (unsigned short*)(ws + 37748736 + 2 * 12582912);
  unsigned short* xb = Qb;
  unsigned short* wqkvb = Kbuf;
  unsigned short* wprojb = Vtb;
  unsigned short* attnb = qkvb;

  // 0. fp32 -> bf16 converts
  cvt_f32_bf16<<<dim3(786432 / 256), 256, 0, stream>>>(x, xb, 786432);
  cvt_f32_bf16<<<dim3(221184 / 256), 256, 0, stream>>>(wqkv, wqkvb, 221184);
  // 1. qkv = x @ w_qkv^T (bf16 out)
  gemm_bt16<1><<<dim3(K3c / 128, Mc / 128), 256, 0, stream>>>(xb, wqkvb, qkvb, nullptr,
                                                              K3c, Cc);
  // 2. RoPE -> Q,K [B,H,N,Dh]
  rope_qk<<<dim3(Bc * Nc * Hc * 32 / 256), 256, 0, stream>>>(qkvb, fcos, fsin, Qb, Kbuf);
  // 3. V transpose -> Vt [B,H,Dh,N]
  vtrans<<<dim3(Nc / 64, Bc * Hc), 256, 0, stream>>>(qkvb, Vtb);
  // 4. causal attention -> attnb [B,N,C] bf16
  attn_fwd<<<dim3(Nc / 128, Bc * Hc), 256, 0, stream>>>(Qb, Kbuf, Vtb, attnb);
  // 5. out = attn @ w_proj^T + b (fp32 out)
  cvt_f32_bf16<<<dim3(73728 / 256), 256, 0, stream>>>(wproj, wprojb, 73728);
  gemm_bt16<0><<<dim3(Cc / 128, Mc / 128), 256, 0, stream>>>(attnb, wprojb, d_out, bproj,
                                                             Cc, Cc);
}

// Round 4
// 218.019 us; speedup vs baseline: 1.1670x; 1.0127x over previous
//
#include <hip/hip_runtime.h>
#include <hip/hip_bf16.h>

#define DEVI static __device__ __forceinline__

typedef __attribute__((ext_vector_type(8))) short bf16x8;
typedef __attribute__((ext_vector_type(4))) float f32x4;
typedef __attribute__((ext_vector_type(16))) float f32x16;
typedef __attribute__((ext_vector_type(4))) int i32x4;

constexpr int Bc = 4, Nc = 2048, Cc = 768, Hc = 12, Dhc = 64;
constexpr int Mc = Bc * Nc;   // 8192 tokens
constexpr int K3c = 3 * Cc;   // 2304

// fp32 -> bf16 round-to-nearest-even
DEVI unsigned int f2bf(float f) {
  unsigned int u = __float_as_uint(f);
  return (u + 0x7fffu + ((u >> 16) & 1u)) >> 16;
}
DEVI float bf2f(unsigned int u) { return __uint_as_float(u << 16); }

DEVI unsigned int cvtpk_bf16(float lo, float hi_) {
  unsigned int r;
  asm("v_cvt_pk_bf16_f32 %0, %1, %2" : "=v"(r) : "v"(lo), "v"(hi_));
  return r;
}

#define GLOAD_LDS(g, l)                                                              \
  __builtin_amdgcn_global_load_lds((const __attribute__((address_space(1))) void*)(g), \
                                   (__attribute__((address_space(3))) void*)(l), 16, 0, 0)

// ---------------------------------------------------------------------------
// fp32 -> bf16 bulk convert, 8 elems/thread
// ---------------------------------------------------------------------------
__global__ __launch_bounds__(256) void cvt_f32_bf16(const float* __restrict__ in,
                                                    unsigned short* __restrict__ out, int n8) {
  const int i = blockIdx.x * 256 + threadIdx.x;
  if (i >= n8) return;
  const f32x4 a = *((const f32x4*)in + (size_t)i * 2);
  const f32x4 b = *((const f32x4*)in + (size_t)i * 2 + 1);
  i32x4 v;
  v.x = (int)(f2bf(a.x) | (f2bf(a.y) << 16));
  v.y = (int)(f2bf(a.z) | (f2bf(a.w) << 16));
  v.z = (int)(f2bf(b.x) | (f2bf(b.y) << 16));
  v.w = (int)(f2bf(b.z) | (f2bf(b.w) << 16));
  *((i32x4*)out + i) = v;
}

// ---------------------------------------------------------------------------
// GEMM: C[M,Nout] = A[M,K] * W[Nout,K]^T, bf16 in. 128x128 tile, BK=64,
// 4 waves (2x2), mfma 16x16x32. Staging via global_load_lds (width 16),
// pre-swizzled global source (slot ^= row&7) + linear LDS + swizzled reads.
// (unchanged from round 3 — passing)
// ---------------------------------------------------------------------------
template <int OBF16>
__global__ __launch_bounds__(256) void gemm_bt16(const unsigned short* __restrict__ Ap,
                                                 const unsigned short* __restrict__ Wp,
                                                 void* __restrict__ Cp,
                                                 const float* __restrict__ bias,
                                                 int Nout, int Kdim) {
  __shared__ unsigned short As[128 * 64];
  __shared__ unsigned short Bs[128 * 64];
  const int tid = threadIdx.x;
  const int bn = blockIdx.x, bm = blockIdx.y;
  const int m0 = bm * 128, n0 = bn * 128;
  const int w = tid >> 6, lane = tid & 63;
  const int wr = w >> 1, wc = w & 1;
  const int lr = lane & 15, lg = lane >> 4;
  const int r = lane >> 3, slot = lane & 7;

  f32x4 acc[4][4];
#pragma unroll
  for (int i = 0; i < 4; ++i)
#pragma unroll
    for (int j = 0; j < 4; ++j) acc[i][j] = f32x4{0.f, 0.f, 0.f, 0.f};

  for (int kt = 0; kt < Kdim; kt += 64) {
    __syncthreads();
#pragma unroll
    for (int c = 0; c < 4; ++c) {
      const int i = (w << 2) + c;
      const int row = (i << 3) + r;
      const unsigned short* ga = Ap + (size_t)(m0 + row) * Kdim + kt + ((slot ^ r) << 3);
      GLOAD_LDS(ga, As + (i << 9));
      const unsigned short* gb = Wp + (size_t)(n0 + row) * Kdim + kt + ((slot ^ r) << 3);
      GLOAD_LDS(gb, Bs + (i << 9));
    }
    __syncthreads();

    bf16x8 af[4][2], bfr[4][2];
#pragma unroll
    for (int mf = 0; mf < 4; ++mf) {
      const int row = wr * 64 + mf * 16 + lr;
#pragma unroll
      for (int kk = 0; kk < 2; ++kk)
        af[mf][kk] = *(const bf16x8*)&As[row * 64 + (((kk * 4 + lg) ^ (row & 7)) * 8)];
    }
#pragma unroll
    for (int nf = 0; nf < 4; ++nf) {
      const int row = wc * 64 + nf * 16 + lr;
#pragma unroll
      for (int kk = 0; kk < 2; ++kk)
        bfr[nf][kk] = *(const bf16x8*)&Bs[row * 64 + (((kk * 4 + lg) ^ (row & 7)) * 8)];
    }
#pragma unroll
    for (int mf = 0; mf < 4; ++mf)
#pragma unroll
      for (int nf = 0; nf < 4; ++nf)
#pragma unroll
        for (int kk = 0; kk < 2; ++kk)
          acc[mf][nf] = __builtin_amdgcn_mfma_f32_16x16x32_bf16(af[mf][kk], bfr[nf][kk],
                                                                acc[mf][nf], 0, 0, 0);
  }

#pragma unroll
  for (int mf = 0; mf < 4; ++mf) {
#pragma unroll
    for (int nf = 0; nf < 4; ++nf) {
      const int col = n0 + wc * 64 + nf * 16 + lr;
#pragma unroll
      for (int rg = 0; rg < 4; ++rg) {
        const int rowg = m0 + wr * 64 + mf * 16 + lg * 4 + rg;
        const float v = acc[mf][nf][rg];
        if constexpr (OBF16) {
          ((unsigned short*)Cp)[(size_t)rowg * Nout + col] = (unsigned short)f2bf(v);
        } else {
          ((float*)Cp)[(size_t)rowg * Nout + col] = v + bias[col];
        }
      }
    }
  }
}

// ---------------------------------------------------------------------------
// RoPE on q,k: qkv [B,N,3,H,Dh] bf16 -> Q,K [B,H,N,Dh] bf16.
// Q is PRE-SCALED by KL = (1/sqrt(Dh))*log2(e) so attention's QK^T lands
// directly in the exp2 domain (saves 32 v_mul per kv-tile per lane).
// ---------------------------------------------------------------------------
__global__ __launch_bounds__(256) void rope_qk(const unsigned short* __restrict__ qkv,
                                               const float* __restrict__ fcos,
                                               const float* __restrict__ fsin,
                                               unsigned short* __restrict__ Qo,
                                               unsigned short* __restrict__ Ko) {
  constexpr float KL = 0.18033688011112042f;  // (1/sqrt(64)) * log2(e)
  const int idx = blockIdx.x * 256 + threadIdx.x;
  if (idx >= Bc * Nc * Hc * 32) return;
  const int dp = idx & 31;
  const int t = idx >> 5;
  const int h = t % Hc;
  const int bn = t / Hc;
  const int n = bn & (Nc - 1);
  const int b = bn >> 11;
  const size_t qoff = (size_t)bn * 3 * Cc + h * 64 + dp * 2;
  const unsigned int qp = *(const unsigned int*)&qkv[qoff];
  const unsigned int kp = *(const unsigned int*)&qkv[qoff + Cc];
  const float c = fcos[n * 32 + dp], s = fsin[n * 32 + dp];
  const float qa = bf2f(qp & 0xffffu), qb = bf2f(qp >> 16);
  const float ka = bf2f(kp & 0xffffu), kb = bf2f(kp >> 16);
  const unsigned int qo = f2bf(KL * (qa * c - qb * s)) | (f2bf(KL * (qa * s + qb * c)) << 16);
  const unsigned int ko = f2bf(ka * c - kb * s) | (f2bf(ka * s + kb * c) << 16);
  const size_t o = ((size_t)((b * Hc + h) * Nc) + n) * Dhc + dp * 2;
  *(unsigned int*)&Qo[o] = qo;
  *(unsigned int*)&Ko[o] = ko;
}

// ---------------------------------------------------------------------------
// V transpose: qkv v-slice [B,N,H,Dh] -> Vt [B,H,Dh,N]  (unchanged)
// ---------------------------------------------------------------------------
__global__ __launch_bounds__(256) void vtrans(const unsigned short* __restrict__ qkv,
                                              unsigned short* __restrict__ Vt) {
  __shared__ unsigned short tile[64 * 72];
  const int nt = blockIdx.x, bh = blockIdx.y;
  const int b = bh / Hc, h = bh % Hc;
  const int tid = threadIdx.x;
  const int n0 = nt * 64;
  const int rrow = tid >> 3, rslot = tid & 7;
#pragma unroll
  for (int it = 0; it < 2; ++it) {
    const int n = it * 32 + rrow;
    i32x4 v = *(const i32x4*)&qkv[((size_t)(b * Nc + n0 + n) * 3 + 2) * Cc + h * 64 + rslot * 8];
    *(i32x4*)&tile[n * 72 + rslot * 8] = v;
  }
  __syncthreads();
#pragma unroll
  for (int it = 0; it < 2; ++it) {
    const int task = it * 256 + tid;
    const int d = task >> 3, ns = task & 7;
    unsigned short tmp[8];
#pragma unroll
    for (int j = 0; j < 8; ++j) tmp[j] = tile[(ns * 8 + j) * 72 + d];
    *(i32x4*)&Vt[((size_t)(bh * Dhc + d)) * Nc + n0 + ns * 8] = *(const i32x4*)tmp;
  }
}

// ---------------------------------------------------------------------------
// Causal flash attention — barrier-free / LDS-free.
// 4 waves x 32 q-rows = 128 q/block; each wave fully independent: loads its
// K and V^T MFMA fragments straight from global (KV per head = 512 KB;
// block mapping pins each bh to ONE XCD so its KV is L2-resident, and the
// 4 waves of a block stream the same tiles ~in step -> L1 reuse).
// Fragment math identical to the round-3 passing kernel (swapped QK^T,
// mfma 32x32x16, T12 cvt_pk+permlane32_swap, T13 defer-max). Q pre-scaled
// by KL at rope. No __syncthreads, no LDS, no vmcnt(0) drains.
// Block mapping: id = 8*(6*qg + bhi) + x8 -> bh = x8 + 8*bhi (XCD = x8),
// qtile = 15 - qg (heavy-first within each XCD).
// ---------------------------------------------------------------------------
__global__ __launch_bounds__(256, 3) void attn_fwd(const unsigned short* __restrict__ Qp,
                                                   const unsigned short* __restrict__ Kp,
                                                   const unsigned short* __restrict__ Vtp,
                                                   unsigned short* __restrict__ Op) {
  const int id = blockIdx.x;
  const int x8 = id & 7;
  const int r = id >> 3;
  const int qg = r / 6;
  const int bh = x8 + ((r % 6) << 3);
  const int q0 = (15 - qg) * 128;
  const int tid = threadIdx.x, w = tid >> 6, lane = tid & 63;
  const int qc = lane & 31, hi = lane >> 5;
  const int qw0 = q0 + w * 32;        // wave's first q-row
  const int qrow = qw0 + qc;          // this lane's q index
  const int qwmax = qw0 + 31;
  const unsigned short* Kb = Kp + (size_t)bh * (Nc * 64);
  const unsigned short* Vb = Vtp + (size_t)bh * (64 * Nc);

  bf16x8 qf[4];
  {
    const unsigned short* qptr = Qp + ((size_t)bh * Nc + qrow) * 64 + hi * 8;
#pragma unroll
    for (int ks = 0; ks < 4; ++ks) qf[ks] = *(const bf16x8*)(qptr + ks * 16);
  }

  f32x16 oacc[2];
#pragma unroll
  for (int dt = 0; dt < 2; ++dt)
#pragma unroll
    for (int j = 0; j < 16; ++j) oacc[dt][j] = 0.f;
  float m_run = -1e30f, l_run = 0.f;

  for (int k0 = 0; k0 <= qwmax; k0 += 64) {
    // --- K fragments straight from global (row-major [N][64])
    const unsigned short* kp0 = Kb + ((size_t)(k0 + qc) << 6) + (hi << 3);
    bf16x8 kf[2][4];
#pragma unroll
    for (int f = 0; f < 2; ++f)
#pragma unroll
      for (int ks = 0; ks < 4; ++ks)
        kf[f][ks] = *(const bf16x8*)(kp0 + (f << 11) + (ks << 4));

    // --- QK^T : S^T[kv][q] (already in exp2 domain; Q pre-scaled)
    f32x16 sacc[2];
#pragma unroll
    for (int f = 0; f < 2; ++f)
#pragma unroll
      for (int j = 0; j < 16; ++j) sacc[f][j] = 0.f;
#pragma unroll
    for (int f = 0; f < 2; ++f)
#pragma unroll
      for (int ks = 0; ks < 4; ++ks)
        sacc[f] = __builtin_amdgcn_mfma_f32_32x32x16_bf16(kf[f][ks], qf[ks], sacc[f], 0, 0, 0);

    // --- V fragments (issued now; consumed after softmax -> latency hidden)
    const unsigned short* vp0 = Vb + ((size_t)qc * Nc) + k0 + (hi << 3);
    bf16x8 vf[2][4];
#pragma unroll
    for (int dt = 0; dt < 2; ++dt)
#pragma unroll
      for (int ks = 0; ks < 4; ++ks)
        vf[dt][ks] = *(const bf16x8*)(vp0 + ((size_t)dt << 16) + (ks << 4));

    // --- online softmax; lane kv rows: f*32 + (rr&3) + 8*(rr>>2) + 4*hi
    const bool masked = (k0 + 63 > qw0);
    float pmax = -1e30f;
#pragma unroll
    for (int f = 0; f < 2; ++f)
#pragma unroll
      for (int rr = 0; rr < 16; ++rr) {
        float v = sacc[f][rr];
        if (masked) {
          const int kvi = k0 + f * 32 + (rr & 3) + ((rr >> 2) << 3) + (hi << 2);
          v = (kvi <= qrow) ? v : -1e30f;
        }
        pmax = fmaxf(pmax, v);
      }
    pmax = fmaxf(pmax, __shfl_xor(pmax, 32, 64));
    if (!__all(pmax - m_run <= 11.5f)) {  // defer-max (T13)
      const float m_new = fmaxf(m_run, pmax);
      const float rs = exp2f(m_run - m_new);
      l_run *= rs;
#pragma unroll
      for (int dt = 0; dt < 2; ++dt)
#pragma unroll
        for (int j = 0; j < 16; ++j) oacc[dt][j] *= rs;
      m_run = m_new;
    }

    float psum = 0.f;
    unsigned int pw[2][8];
#pragma unroll
    for (int f = 0; f < 2; ++f) {
      float p[16];
#pragma unroll
      for (int rr = 0; rr < 16; ++rr) {
        float p_ = exp2f(sacc[f][rr] - m_run);
        if (masked) {
          const int kvi = k0 + f * 32 + (rr & 3) + ((rr >> 2) << 3) + (hi << 2);
          p_ = (kvi <= qrow) ? p_ : 0.f;
        }
        p[rr] = p_;
        psum += p_;
      }
#pragma unroll
      for (int j = 0; j < 8; ++j) pw[f][j] = cvtpk_bf16(p[2 * j], p[2 * j + 1]);
      // T12: earlier-kv word is vdst (vdst[32:63] <-> vsrc[0:31])
      asm volatile("v_permlane32_swap_b32 %0, %1" : "+v"(pw[f][0]), "+v"(pw[f][2]));
      asm volatile("v_permlane32_swap_b32 %0, %1" : "+v"(pw[f][1]), "+v"(pw[f][3]));
      asm volatile("v_permlane32_swap_b32 %0, %1" : "+v"(pw[f][4]), "+v"(pw[f][6]));
      asm volatile("v_permlane32_swap_b32 %0, %1" : "+v"(pw[f][5]), "+v"(pw[f][7]));
    }
    psum += __shfl_xor(psum, 32, 64);
    l_run += psum;

    // --- PV: O^T[d][q] += V^T x P
#pragma unroll
    for (int dt = 0; dt < 2; ++dt)
#pragma unroll
      for (int ks = 0; ks < 4; ++ks) {
        i32x4 pi;
        pi.x = (int)pw[ks >> 1][(ks & 1) * 4 + 0];
        pi.y = (int)pw[ks >> 1][(ks & 1) * 4 + 1];
        pi.z = (int)pw[ks >> 1][(ks & 1) * 4 + 2];
        pi.w = (int)pw[ks >> 1][(ks & 1) * 4 + 3];
        bf16x8 pf = __builtin_bit_cast(bf16x8, pi);
        oacc[dt] = __builtin_amdgcn_mfma_f32_32x32x16_bf16(vf[dt][ks], pf, oacc[dt], 0, 0, 0);
      }
  }

  // --- epilogue: lane owns q column; d = dt*32 + rq*8 + hi*4 + (0..3)
  const float inv = 1.f / l_run;
  const int b = bh / Hc, h = bh % Hc;
  unsigned short* orow = Op + ((size_t)(b * Nc + qrow)) * Cc + h * 64;
#pragma unroll
  for (int dt = 0; dt < 2; ++dt)
#pragma unroll
    for (int rq = 0; rq < 4; ++rq) {
      const float o0 = oacc[dt][rq * 4 + 0] * inv;
      const float o1 = oacc[dt][rq * 4 + 1] * inv;
      const float o2 = oacc[dt][rq * 4 + 2] * inv;
      const float o3 = oacc[dt][rq * 4 + 3] * inv;
      uint2 val;
      val.x = f2bf(o0) | (f2bf(o1) << 16);
      val.y = f2bf(o2) | (f2bf(o3) << 16);
      *(uint2*)(orow + dt * 32 + rq * 8 + hi * 4) = val;
    }
}

// ---------------------------------------------------------------------------
// Workspace layout (75,497,472 B total):
//   [0,       37.75M) qkv bf16          (later reused as attn output)
//   [37.75M, +12.58M) x_bf16, then Q    (x dead before rope writes Q)
//   [50.33M, +12.58M) wqkv_bf16, then K (dead before rope writes K)
//   [62.91M, +12.58M) Vt, then wproj_bf16 after attn consumes Vt
// ---------------------------------------------------------------------------
extern "C" void kernel_launch(void* const* d_in, const int* in_sizes, int n_in,
                              void* d_out, int out_size, void* d_ws, size_t ws_size,
                              hipStream_t stream) {
  const float* x = (const float*)d_in[0];
  const float* fcos = (const float*)d_in[1];
  const float* fsin = (const float*)d_in[2];
  // d_in[3] (mask) unused: causal structure applied analytically
  const float* wqkv = (const float*)d_in[4];
  const float* wproj = (const float*)d_in[5];
  const float* bproj = (const float*)d_in[6];

  char* ws = (char*)d_ws;
  unsigned short* qkvb = (unsigned short*)ws;
  unsigned short* Qb = (unsigned short*)(ws + 37748736);
  unsigned short* Kbuf = (unsigned short*)(ws + 37748736 + 12582912);
  unsigned short* Vtb = (unsigned short*)(ws + 37748736 + 2 * 12582912);
  unsigned short* xb = Qb;
  unsigned short* wqkvb = Kbuf;
  unsigned short* wprojb = Vtb;
  unsigned short* attnb = qkvb;

  // 0. fp32 -> bf16 converts
  cvt_f32_bf16<<<dim3(786432 / 256), 256, 0, stream>>>(x, xb, 786432);
  cvt_f32_bf16<<<dim3(221184 / 256), 256, 0, stream>>>(wqkv, wqkvb, 221184);
  // 1. qkv = x @ w_qkv^T (bf16 out)
  gemm_bt16<1><<<dim3(K3c / 128, Mc / 128), 256, 0, stream>>>(xb, wqkvb, qkvb, nullptr,
                                                              K3c, Cc);
  // 2. RoPE -> Q,K [B,H,N,Dh] (Q pre-scaled by KL)
  rope_qk<<<dim3(Bc * Nc * Hc * 32 / 256), 256, 0, stream>>>(qkvb, fcos, fsin, Qb, Kbuf);
  // 3. V transpose -> Vt [B,H,Dh,N]
  vtrans<<<dim3(Nc / 64, Bc * Hc), 256, 0, stream>>>(qkvb, Vtb);
  // 4. causal attention -> attnb [B,N,C] bf16 (768 blocks, XCD-pinned bh)
  attn_fwd<<<dim3(768), 256, 0, stream>>>(Qb, Kbuf, Vtb, attnb);
  // 5. out = attn @ w_proj^T + b (fp32 out)
  cvt_f32_bf16<<<dim3(73728 / 256), 256, 0, stream>>>(wproj, wprojb, 73728);
  gemm_bt16<0><<<dim3(Cc / 128, Mc / 128), 256, 0, stream>>>(attnb, wprojb, d_out, bproj,
                                                             Cc, Cc);
}

// Round 5
// 216.541 us; speedup vs baseline: 1.1749x; 1.0068x over previous
//
#include <hip/hip_runtime.h>
#include <hip/hip_bf16.h>

#define DEVI static __device__ __forceinline__

typedef __attribute__((ext_vector_type(8))) short bf16x8;
typedef __attribute__((ext_vector_type(4))) float f32x4;
typedef __attribute__((ext_vector_type(16))) float f32x16;
typedef __attribute__((ext_vector_type(4))) int i32x4;

constexpr int Bc = 4, Nc = 2048, Cc = 768, Hc = 12, Dhc = 64;
constexpr int Mc = Bc * Nc;   // 8192 tokens
constexpr int K3c = 3 * Cc;   // 2304

// fp32 -> bf16 round-to-nearest-even
DEVI unsigned int f2bf(float f) {
  unsigned int u = __float_as_uint(f);
  return (u + 0x7fffu + ((u >> 16) & 1u)) >> 16;
}
DEVI float bf2f(unsigned int u) { return __uint_as_float(u << 16); }

DEVI unsigned int cvtpk_bf16(float lo, float hi_) {
  unsigned int r;
  asm("v_cvt_pk_bf16_f32 %0, %1, %2" : "=v"(r) : "v"(lo), "v"(hi_));
  return r;
}

// Raw v_exp_f32 (2^x). libm exp2f is a multi-instruction OCML routine —
// it was ~1000 VALU insts/iteration in rounds 1-4 (the attn bottleneck).
#if __has_builtin(__builtin_amdgcn_exp2f)
#define EXP2(x) __builtin_amdgcn_exp2f(x)
#else
#define EXP2(x) exp2f(x)
#endif

#define GLOAD_LDS(g, l)                                                              \
  __builtin_amdgcn_global_load_lds((const __attribute__((address_space(1))) void*)(g), \
                                   (__attribute__((address_space(3))) void*)(l), 16, 0, 0)

// ---------------------------------------------------------------------------
// fp32 -> bf16 bulk convert, 8 elems/thread
// ---------------------------------------------------------------------------
__global__ __launch_bounds__(256) void cvt_f32_bf16(const float* __restrict__ in,
                                                    unsigned short* __restrict__ out, int n8) {
  const int i = blockIdx.x * 256 + threadIdx.x;
  if (i >= n8) return;
  const f32x4 a = *((const f32x4*)in + (size_t)i * 2);
  const f32x4 b = *((const f32x4*)in + (size_t)i * 2 + 1);
  i32x4 v;
  v.x = (int)(f2bf(a.x) | (f2bf(a.y) << 16));
  v.y = (int)(f2bf(a.z) | (f2bf(a.w) << 16));
  v.z = (int)(f2bf(b.x) | (f2bf(b.y) << 16));
  v.w = (int)(f2bf(b.z) | (f2bf(b.w) << 16));
  *((i32x4*)out + i) = v;
}

// ---------------------------------------------------------------------------
// GEMM: C[M,Nout] = A[M,K] * W[Nout,K]^T, bf16 in. 128x128 tile, BK=64,
// 4 waves (2x2), mfma 16x16x32. Staging via global_load_lds (width 16),
// pre-swizzled global source (slot ^= row&7) + linear LDS + swizzled reads.
// (unchanged — passing)
// ---------------------------------------------------------------------------
template <int OBF16>
__global__ __launch_bounds__(256) void gemm_bt16(const unsigned short* __restrict__ Ap,
                                                 const unsigned short* __restrict__ Wp,
                                                 void* __restrict__ Cp,
                                                 const float* __restrict__ bias,
                                                 int Nout, int Kdim) {
  __shared__ unsigned short As[128 * 64];
  __shared__ unsigned short Bs[128 * 64];
  const int tid = threadIdx.x;
  const int bn = blockIdx.x, bm = blockIdx.y;
  const int m0 = bm * 128, n0 = bn * 128;
  const int w = tid >> 6, lane = tid & 63;
  const int wr = w >> 1, wc = w & 1;
  const int lr = lane & 15, lg = lane >> 4;
  const int r = lane >> 3, slot = lane & 7;

  f32x4 acc[4][4];
#pragma unroll
  for (int i = 0; i < 4; ++i)
#pragma unroll
    for (int j = 0; j < 4; ++j) acc[i][j] = f32x4{0.f, 0.f, 0.f, 0.f};

  for (int kt = 0; kt < Kdim; kt += 64) {
    __syncthreads();
#pragma unroll
    for (int c = 0; c < 4; ++c) {
      const int i = (w << 2) + c;
      const int row = (i << 3) + r;
      const unsigned short* ga = Ap + (size_t)(m0 + row) * Kdim + kt + ((slot ^ r) << 3);
      GLOAD_LDS(ga, As + (i << 9));
      const unsigned short* gb = Wp + (size_t)(n0 + row) * Kdim + kt + ((slot ^ r) << 3);
      GLOAD_LDS(gb, Bs + (i << 9));
    }
    __syncthreads();

    bf16x8 af[4][2], bfr[4][2];
#pragma unroll
    for (int mf = 0; mf < 4; ++mf) {
      const int row = wr * 64 + mf * 16 + lr;
#pragma unroll
      for (int kk = 0; kk < 2; ++kk)
        af[mf][kk] = *(const bf16x8*)&As[row * 64 + (((kk * 4 + lg) ^ (row & 7)) * 8)];
    }
#pragma unroll
    for (int nf = 0; nf < 4; ++nf) {
      const int row = wc * 64 + nf * 16 + lr;
#pragma unroll
      for (int kk = 0; kk < 2; ++kk)
        bfr[nf][kk] = *(const bf16x8*)&Bs[row * 64 + (((kk * 4 + lg) ^ (row & 7)) * 8)];
    }
#pragma unroll
    for (int mf = 0; mf < 4; ++mf)
#pragma unroll
      for (int nf = 0; nf < 4; ++nf)
#pragma unroll
        for (int kk = 0; kk < 2; ++kk)
          acc[mf][nf] = __builtin_amdgcn_mfma_f32_16x16x32_bf16(af[mf][kk], bfr[nf][kk],
                                                                acc[mf][nf], 0, 0, 0);
  }

#pragma unroll
  for (int mf = 0; mf < 4; ++mf) {
#pragma unroll
    for (int nf = 0; nf < 4; ++nf) {
      const int col = n0 + wc * 64 + nf * 16 + lr;
#pragma unroll
      for (int rg = 0; rg < 4; ++rg) {
        const int rowg = m0 + wr * 64 + mf * 16 + lg * 4 + rg;
        const float v = acc[mf][nf][rg];
        if constexpr (OBF16) {
          ((unsigned short*)Cp)[(size_t)rowg * Nout + col] = (unsigned short)f2bf(v);
        } else {
          ((float*)Cp)[(size_t)rowg * Nout + col] = v + bias[col];
        }
      }
    }
  }
}

// ---------------------------------------------------------------------------
// RoPE on q,k: qkv [B,N,3,H,Dh] bf16 -> Q,K [B,H,N,Dh] bf16.
// Q is PRE-SCALED by KL = (1/sqrt(Dh))*log2(e) so attention's QK^T lands
// directly in the exp2 domain.
// ---------------------------------------------------------------------------
__global__ __launch_bounds__(256) void rope_qk(const unsigned short* __restrict__ qkv,
                                               const float* __restrict__ fcos,
                                               const float* __restrict__ fsin,
                                               unsigned short* __restrict__ Qo,
                                               unsigned short* __restrict__ Ko) {
  constexpr float KL = 0.18033688011112042f;  // (1/sqrt(64)) * log2(e)
  const int idx = blockIdx.x * 256 + threadIdx.x;
  if (idx >= Bc * Nc * Hc * 32) return;
  const int dp = idx & 31;
  const int t = idx >> 5;
  const int h = t % Hc;
  const int bn = t / Hc;
  const int n = bn & (Nc - 1);
  const int b = bn >> 11;
  const size_t qoff = (size_t)bn * 3 * Cc + h * 64 + dp * 2;
  const unsigned int qp = *(const unsigned int*)&qkv[qoff];
  const unsigned int kp = *(const unsigned int*)&qkv[qoff + Cc];
  const float c = fcos[n * 32 + dp], s = fsin[n * 32 + dp];
  const float qa = bf2f(qp & 0xffffu), qb = bf2f(qp >> 16);
  const float ka = bf2f(kp & 0xffffu), kb = bf2f(kp >> 16);
  const unsigned int qo = f2bf(KL * (qa * c - qb * s)) | (f2bf(KL * (qa * s + qb * c)) << 16);
  const unsigned int ko = f2bf(ka * c - kb * s) | (f2bf(ka * s + kb * c) << 16);
  const size_t o = ((size_t)((b * Hc + h) * Nc) + n) * Dhc + dp * 2;
  *(unsigned int*)&Qo[o] = qo;
  *(unsigned int*)&Ko[o] = ko;
}

// ---------------------------------------------------------------------------
// V transpose: qkv v-slice [B,N,H,Dh] -> Vt [B,H,Dh,N]  (unchanged)
// ---------------------------------------------------------------------------
__global__ __launch_bounds__(256) void vtrans(const unsigned short* __restrict__ qkv,
                                              unsigned short* __restrict__ Vt) {
  __shared__ unsigned short tile[64 * 72];
  const int nt = blockIdx.x, bh = blockIdx.y;
  const int b = bh / Hc, h = bh % Hc;
  const int tid = threadIdx.x;
  const int n0 = nt * 64;
  const int rrow = tid >> 3, rslot = tid & 7;
#pragma unroll
  for (int it = 0; it < 2; ++it) {
    const int n = it * 32 + rrow;
    i32x4 v = *(const i32x4*)&qkv[((size_t)(b * Nc + n0 + n) * 3 + 2) * Cc + h * 64 + rslot * 8];
    *(i32x4*)&tile[n * 72 + rslot * 8] = v;
  }
  __syncthreads();
#pragma unroll
  for (int it = 0; it < 2; ++it) {
    const int task = it * 256 + tid;
    const int d = task >> 3, ns = task & 7;
    unsigned short tmp[8];
#pragma unroll
    for (int j = 0; j < 8; ++j) tmp[j] = tile[(ns * 8 + j) * 72 + d];
    *(i32x4*)&Vt[((size_t)(bh * Dhc + d)) * Nc + n0 + ns * 8] = *(const i32x4*)tmp;
  }
}

// ---------------------------------------------------------------------------
// Causal flash attention — barrier-free / LDS-free (round-4 structure).
// Round-5 changes: (1) raw v_exp_f32 via EXP2 (libm exp2f was ~30+ insts
// per call = the measured ~1000 VALU insts/iter); (2) causal mask folded
// into sacc once (exp of -1e30 underflows to 0, no second mask pass);
// (3) pmax/psum as depth-5 trees instead of 32-deep serial chains.
// ---------------------------------------------------------------------------
__global__ __launch_bounds__(256, 3) void attn_fwd(const unsigned short* __restrict__ Qp,
                                                   const unsigned short* __restrict__ Kp,
                                                   const unsigned short* __restrict__ Vtp,
                                                   unsigned short* __restrict__ Op) {
  const int id = blockIdx.x;
  const int x8 = id & 7;
  const int r = id >> 3;
  const int qg = r / 6;
  const int bh = x8 + ((r % 6) << 3);
  const int q0 = (15 - qg) * 128;
  const int tid = threadIdx.x, w = tid >> 6, lane = tid & 63;
  const int qc = lane & 31, hi = lane >> 5;
  const int qw0 = q0 + w * 32;        // wave's first q-row
  const int qrow = qw0 + qc;          // this lane's q index
  const int qwmax = qw0 + 31;
  const unsigned short* Kb = Kp + (size_t)bh * (Nc * 64);
  const unsigned short* Vb = Vtp + (size_t)bh * (64 * Nc);

  bf16x8 qf[4];
  {
    const unsigned short* qptr = Qp + ((size_t)bh * Nc + qrow) * 64 + hi * 8;
#pragma unroll
    for (int ks = 0; ks < 4; ++ks) qf[ks] = *(const bf16x8*)(qptr + ks * 16);
  }

  f32x16 oacc[2];
#pragma unroll
  for (int dt = 0; dt < 2; ++dt)
#pragma unroll
    for (int j = 0; j < 16; ++j) oacc[dt][j] = 0.f;
  float m_run = -1e30f, l_run = 0.f;

  for (int k0 = 0; k0 <= qwmax; k0 += 64) {
    // --- K fragments straight from global (row-major [N][64])
    const unsigned short* kp0 = Kb + ((size_t)(k0 + qc) << 6) + (hi << 3);
    bf16x8 kf[2][4];
#pragma unroll
    for (int f = 0; f < 2; ++f)
#pragma unroll
      for (int ks = 0; ks < 4; ++ks)
        kf[f][ks] = *(const bf16x8*)(kp0 + (f << 11) + (ks << 4));

    // --- QK^T : S^T[kv][q] (already in exp2 domain; Q pre-scaled)
    f32x16 sacc[2];
#pragma unroll
    for (int f = 0; f < 2; ++f)
#pragma unroll
      for (int j = 0; j < 16; ++j) sacc[f][j] = 0.f;
#pragma unroll
    for (int f = 0; f < 2; ++f)
#pragma unroll
      for (int ks = 0; ks < 4; ++ks)
        sacc[f] = __builtin_amdgcn_mfma_f32_32x32x16_bf16(kf[f][ks], qf[ks], sacc[f], 0, 0, 0);

    // --- V fragments (issued now; consumed after softmax -> latency hidden)
    const unsigned short* vp0 = Vb + ((size_t)qc * Nc) + k0 + (hi << 3);
    bf16x8 vf[2][4];
#pragma unroll
    for (int dt = 0; dt < 2; ++dt)
#pragma unroll
      for (int ks = 0; ks < 4; ++ks)
        vf[dt][ks] = *(const bf16x8*)(vp0 + ((size_t)dt << 16) + (ks << 4));

    // --- causal mask folded into sacc (once); lane kv row:
    //     f*32 + (rr&3) + 8*(rr>>2) + 4*hi
    if (k0 + 63 > qw0) {
#pragma unroll
      for (int f = 0; f < 2; ++f)
#pragma unroll
        for (int rr = 0; rr < 16; ++rr) {
          const int kvi = k0 + f * 32 + (rr & 3) + ((rr >> 2) << 3) + (hi << 2);
          if (kvi > qrow) sacc[f][rr] = -1e30f;
        }
    }

    // --- online softmax: tree max
    float mx[16];
#pragma unroll
    for (int j = 0; j < 16; ++j) mx[j] = fmaxf(sacc[0][j], sacc[1][j]);
#pragma unroll
    for (int st = 8; st >= 1; st >>= 1)
#pragma unroll
      for (int j = 0; j < st; ++j) mx[j] = fmaxf(mx[j], mx[j + st]);
    const float pmax = fmaxf(mx[0], __shfl_xor(mx[0], 32, 64));

    if (!__all(pmax - m_run <= 11.5f)) {  // defer-max (T13)
      const float m_new = fmaxf(m_run, pmax);
      const float rs = EXP2(m_run - m_new);
      l_run *= rs;
#pragma unroll
      for (int dt = 0; dt < 2; ++dt)
#pragma unroll
        for (int j = 0; j < 16; ++j) oacc[dt][j] *= rs;
      m_run = m_new;
    }

    // --- P = exp2(S - m); masked entries underflow to 0 (arg ~ -1e30)
    float p[32];
#pragma unroll
    for (int f = 0; f < 2; ++f)
#pragma unroll
      for (int rr = 0; rr < 16; ++rr) p[f * 16 + rr] = EXP2(sacc[f][rr] - m_run);

    // tree sum
    float ts[16];
#pragma unroll
    for (int j = 0; j < 16; ++j) ts[j] = p[j] + p[16 + j];
#pragma unroll
    for (int st = 8; st >= 1; st >>= 1)
#pragma unroll
      for (int j = 0; j < st; ++j) ts[j] += ts[j + st];
    l_run += ts[0] + __shfl_xor(ts[0], 32, 64);

    unsigned int pw[2][8];
#pragma unroll
    for (int f = 0; f < 2; ++f) {
#pragma unroll
      for (int j = 0; j < 8; ++j)
        pw[f][j] = cvtpk_bf16(p[f * 16 + 2 * j], p[f * 16 + 2 * j + 1]);
      // T12: earlier-kv word is vdst (vdst[32:63] <-> vsrc[0:31])
      asm volatile("v_permlane32_swap_b32 %0, %1" : "+v"(pw[f][0]), "+v"(pw[f][2]));
      asm volatile("v_permlane32_swap_b32 %0, %1" : "+v"(pw[f][1]), "+v"(pw[f][3]));
      asm volatile("v_permlane32_swap_b32 %0, %1" : "+v"(pw[f][4]), "+v"(pw[f][6]));
      asm volatile("v_permlane32_swap_b32 %0, %1" : "+v"(pw[f][5]), "+v"(pw[f][7]));
    }

    // --- PV: O^T[d][q] += V^T x P
#pragma unroll
    for (int dt = 0; dt < 2; ++dt)
#pragma unroll
      for (int ks = 0; ks < 4; ++ks) {
        i32x4 pi;
        pi.x = (int)pw[ks >> 1][(ks & 1) * 4 + 0];
        pi.y = (int)pw[ks >> 1][(ks & 1) * 4 + 1];
        pi.z = (int)pw[ks >> 1][(ks & 1) * 4 + 2];
        pi.w = (int)pw[ks >> 1][(ks & 1) * 4 + 3];
        bf16x8 pf = __builtin_bit_cast(bf16x8, pi);
        oacc[dt] = __builtin_amdgcn_mfma_f32_32x32x16_bf16(vf[dt][ks], pf, oacc[dt], 0, 0, 0);
      }
  }

  // --- epilogue: lane owns q column; d = dt*32 + rq*8 + hi*4 + (0..3)
  const float inv = 1.f / l_run;
  const int b = bh / Hc, h = bh % Hc;
  unsigned short* orow = Op + ((size_t)(b * Nc + qrow)) * Cc + h * 64;
#pragma unroll
  for (int dt = 0; dt < 2; ++dt)
#pragma unroll
    for (int rq = 0; rq < 4; ++rq) {
      const float o0 = oacc[dt][rq * 4 + 0] * inv;
      const float o1 = oacc[dt][rq * 4 + 1] * inv;
      const float o2 = oacc[dt][rq * 4 + 2] * inv;
      const float o3 = oacc[dt][rq * 4 + 3] * inv;
      uint2 val;
      val.x = f2bf(o0) | (f2bf(o1) << 16);
      val.y = f2bf(o2) | (f2bf(o3) << 16);
      *(uint2*)(orow + dt * 32 + rq * 8 + hi * 4) = val;
    }
}

// ---------------------------------------------------------------------------
// Workspace layout (75,497,472 B total):
//   [0,       37.75M) qkv bf16          (later reused as attn output)
//   [37.75M, +12.58M) x_bf16, then Q    (x dead before rope writes Q)
//   [50.33M, +12.58M) wqkv_bf16, then K (dead before rope writes K)
//   [62.91M, +12.58M) Vt, then wproj_bf16 after attn consumes Vt
// ---------------------------------------------------------------------------
extern "C" void kernel_launch(void* const* d_in, const int* in_sizes, int n_in,
                              void* d_out, int out_size, void* d_ws, size_t ws_size,
                              hipStream_t stream) {
  const float* x = (const float*)d_in[0];
  const float* fcos = (const float*)d_in[1];
  const float* fsin = (const float*)d_in[2];
  // d_in[3] (mask) unused: causal structure applied analytically
  const float* wqkv = (const float*)d_in[4];
  const float* wproj = (const float*)d_in[5];
  const float* bproj = (const float*)d_in[6];

  char* ws = (char*)d_ws;
  unsigned short* qkvb = (unsigned short*)ws;
  unsigned short* Qb = (unsigned short*)(ws + 37748736);
  unsigned short* Kbuf = (unsigned short*)(ws + 37748736 + 12582912);
  unsigned short* Vtb = (unsigned short*)(ws + 37748736 + 2 * 12582912);
  unsigned short* xb = Qb;
  unsigned short* wqkvb = Kbuf;
  unsigned short* wprojb = Vtb;
  unsigned short* attnb = qkvb;

  // 0. fp32 -> bf16 converts
  cvt_f32_bf16<<<dim3(786432 / 256), 256, 0, stream>>>(x, xb, 786432);
  cvt_f32_bf16<<<dim3(221184 / 256), 256, 0, stream>>>(wqkv, wqkvb, 221184);
  // 1. qkv = x @ w_qkv^T (bf16 out)
  gemm_bt16<1><<<dim3(K3c / 128, Mc / 128), 256, 0, stream>>>(xb, wqkvb, qkvb, nullptr,
                                                              K3c, Cc);
  // 2. RoPE -> Q,K [B,H,N,Dh] (Q pre-scaled by KL)
  rope_qk<<<dim3(Bc * Nc * Hc * 32 / 256), 256, 0, stream>>>(qkvb, fcos, fsin, Qb, Kbuf);
  // 3. V transpose -> Vt [B,H,Dh,N]
  vtrans<<<dim3(Nc / 64, Bc * Hc), 256, 0, stream>>>(qkvb, Vtb);
  // 4. causal attention -> attnb [B,N,C] bf16 (768 blocks, XCD-pinned bh)
  attn_fwd<<<dim3(768), 256, 0, stream>>>(Qb, Kbuf, Vtb, attnb);
  // 5. out = attn @ w_proj^T + b (fp32 out)
  cvt_f32_bf16<<<dim3(73728 / 256), 256, 0, stream>>>(wproj, wprojb, 73728);
  gemm_bt16<0><<<dim3(Cc / 128, Mc / 128), 256, 0, stream>>>(attnb, wprojb, d_out, bproj,
                                                             Cc, Cc);
}

// Round 6
// 146.899 us; speedup vs baseline: 1.7319x; 1.4741x over previous
//
#include <hip/hip_runtime.h>
#include <hip/hip_bf16.h>

#define DEVI static __device__ __forceinline__

typedef __attribute__((ext_vector_type(8))) short bf16x8;
typedef __attribute__((ext_vector_type(4))) float f32x4;
typedef __attribute__((ext_vector_type(16))) float f32x16;
typedef __attribute__((ext_vector_type(4))) int i32x4;

constexpr int Bc = 4, Nc = 2048, Cc = 768, Hc = 12, Dhc = 64;
constexpr int Mc = Bc * Nc;   // 8192 tokens
constexpr int K3c = 3 * Cc;   // 2304

// fp32 -> bf16 round-to-nearest-even
DEVI unsigned int f2bf(float f) {
  unsigned int u = __float_as_uint(f);
  return (u + 0x7fffu + ((u >> 16) & 1u)) >> 16;
}
DEVI float bf2f(unsigned int u) { return __uint_as_float(u << 16); }

DEVI unsigned int cvtpk_bf16(float lo, float hi_) {
  unsigned int r;
  asm("v_cvt_pk_bf16_f32 %0, %1, %2" : "=v"(r) : "v"(lo), "v"(hi_));
  return r;
}

// Raw v_exp_f32 (2^x) — libm exp2f is a multi-inst OCML routine (round-4 bug).
#if __has_builtin(__builtin_amdgcn_exp2f)
#define EXP2(x) __builtin_amdgcn_exp2f(x)
#else
#define EXP2(x) exp2f(x)
#endif

#define GLOAD_LDS(g, l)                                                              \
  __builtin_amdgcn_global_load_lds((const __attribute__((address_space(1))) void*)(g), \
                                   (__attribute__((address_space(3))) void*)(l), 16, 0, 0)

// rope on a packed bf16 pair word
DEVI unsigned int rope_pair(unsigned int w, float c, float s) {
  const float a = bf2f(w & 0xffffu), b_ = bf2f(w >> 16);
  return f2bf(a * c - b_ * s) | (f2bf(a * s + b_ * c) << 16);
}

// ---------------------------------------------------------------------------
// fp32 -> bf16 bulk convert, 8 elems/thread
// ---------------------------------------------------------------------------
__global__ __launch_bounds__(256) void cvt_f32_bf16(const float* __restrict__ in,
                                                    unsigned short* __restrict__ out, int n8) {
  const int i = blockIdx.x * 256 + threadIdx.x;
  if (i >= n8) return;
  const f32x4 a = *((const f32x4*)in + (size_t)i * 2);
  const f32x4 b = *((const f32x4*)in + (size_t)i * 2 + 1);
  i32x4 v;
  v.x = (int)(f2bf(a.x) | (f2bf(a.y) << 16));
  v.y = (int)(f2bf(a.z) | (f2bf(a.w) << 16));
  v.z = (int)(f2bf(b.x) | (f2bf(b.y) << 16));
  v.w = (int)(f2bf(b.z) | (f2bf(b.w) << 16));
  *((i32x4*)out + i) = v;
}

// ---------------------------------------------------------------------------
// GEMM: C[M,Nout] = A[M,K] * W[Nout,K]^T, bf16 in. 128x128 tile, BK=64,
// 4 waves (2x2), mfma 16x16x32, global_load_lds staging. (unchanged — passing)
// ---------------------------------------------------------------------------
template <int OBF16>
__global__ __launch_bounds__(256) void gemm_bt16(const unsigned short* __restrict__ Ap,
                                                 const unsigned short* __restrict__ Wp,
                                                 void* __restrict__ Cp,
                                                 const float* __restrict__ bias,
                                                 int Nout, int Kdim) {
  __shared__ unsigned short As[128 * 64];
  __shared__ unsigned short Bs[128 * 64];
  const int tid = threadIdx.x;
  const int bn = blockIdx.x, bm = blockIdx.y;
  const int m0 = bm * 128, n0 = bn * 128;
  const int w = tid >> 6, lane = tid & 63;
  const int wr = w >> 1, wc = w & 1;
  const int lr = lane & 15, lg = lane >> 4;
  const int r = lane >> 3, slot = lane & 7;

  f32x4 acc[4][4];
#pragma unroll
  for (int i = 0; i < 4; ++i)
#pragma unroll
    for (int j = 0; j < 4; ++j) acc[i][j] = f32x4{0.f, 0.f, 0.f, 0.f};

  for (int kt = 0; kt < Kdim; kt += 64) {
    __syncthreads();
#pragma unroll
    for (int c = 0; c < 4; ++c) {
      const int i = (w << 2) + c;
      const int row = (i << 3) + r;
      const unsigned short* ga = Ap + (size_t)(m0 + row) * Kdim + kt + ((slot ^ r) << 3);
      GLOAD_LDS(ga, As + (i << 9));
      const unsigned short* gb = Wp + (size_t)(n0 + row) * Kdim + kt + ((slot ^ r) << 3);
      GLOAD_LDS(gb, Bs + (i << 9));
    }
    __syncthreads();

    bf16x8 af[4][2], bfr[4][2];
#pragma unroll
    for (int mf = 0; mf < 4; ++mf) {
      const int row = wr * 64 + mf * 16 + lr;
#pragma unroll
      for (int kk = 0; kk < 2; ++kk)
        af[mf][kk] = *(const bf16x8*)&As[row * 64 + (((kk * 4 + lg) ^ (row & 7)) * 8)];
    }
#pragma unroll
    for (int nf = 0; nf < 4; ++nf) {
      const int row = wc * 64 + nf * 16 + lr;
#pragma unroll
      for (int kk = 0; kk < 2; ++kk)
        bfr[nf][kk] = *(const bf16x8*)&Bs[row * 64 + (((kk * 4 + lg) ^ (row & 7)) * 8)];
    }
#pragma unroll
    for (int mf = 0; mf < 4; ++mf)
#pragma unroll
      for (int nf = 0; nf < 4; ++nf)
#pragma unroll
        for (int kk = 0; kk < 2; ++kk)
          acc[mf][nf] = __builtin_amdgcn_mfma_f32_16x16x32_bf16(af[mf][kk], bfr[nf][kk],
                                                                acc[mf][nf], 0, 0, 0);
  }

#pragma unroll
  for (int mf = 0; mf < 4; ++mf) {
#pragma unroll
    for (int nf = 0; nf < 4; ++nf) {
      const int col = n0 + wc * 64 + nf * 16 + lr;
#pragma unroll
      for (int rg = 0; rg < 4; ++rg) {
        const int rowg = m0 + wr * 64 + mf * 16 + lg * 4 + rg;
        const float v = acc[mf][nf][rg];
        if constexpr (OBF16) {
          ((unsigned short*)Cp)[(size_t)rowg * Nout + col] = (unsigned short)f2bf(v);
        } else {
          ((float*)Cp)[(size_t)rowg * Nout + col] = v + bias[col];
        }
      }
    }
  }
}

// ---------------------------------------------------------------------------
// RoPE for Q only: qkv [B,N,3,H,Dh] bf16 -> Q [B,H,N,Dh] bf16, pre-scaled
// by KL = (1/sqrt(Dh))*log2(e). (K handled in pack_kv.)
// ---------------------------------------------------------------------------
__global__ __launch_bounds__(256) void rope_q(const unsigned short* __restrict__ qkv,
                                              const float* __restrict__ fcos,
                                              const float* __restrict__ fsin,
                                              unsigned short* __restrict__ Qo) {
  constexpr float KL = 0.18033688011112042f;  // (1/sqrt(64)) * log2(e)
  const int idx = blockIdx.x * 256 + threadIdx.x;
  if (idx >= Bc * Nc * Hc * 32) return;
  const int dp = idx & 31;
  const int t = idx >> 5;
  const int h = t % Hc;
  const int bn = t / Hc;
  const int n = bn & (Nc - 1);
  const int b = bn >> 11;
  const size_t qoff = (size_t)bn * 3 * Cc + h * 64 + dp * 2;
  const unsigned int qp = *(const unsigned int*)&qkv[qoff];
  const float c = fcos[n * 32 + dp], s = fsin[n * 32 + dp];
  const float qa = bf2f(qp & 0xffffu), qb = bf2f(qp >> 16);
  const unsigned int qo = f2bf(KL * (qa * c - qb * s)) | (f2bf(KL * (qa * s + qb * c)) << 16);
  const size_t o = ((size_t)((b * Hc + h) * Nc) + n) * Dhc + dp * 2;
  *(unsigned int*)&Qo[o] = qo;
}

// ---------------------------------------------------------------------------
// pack_kv: per (bh, 64-n tile) build the COALESCED attention layouts:
//   Kc[bh][ch=0..7][n][8]  (d-chunk-major K, rope applied here)
//   Vc[bh][g=n>>3][d][8]   (kv-chunk-major V^T)
// In attn, every K/V fragment load becomes lane-contiguous (qc*16B runs).
// ---------------------------------------------------------------------------
__global__ __launch_bounds__(256) void pack_kv(const unsigned short* __restrict__ qkv,
                                               const float* __restrict__ fcos,
                                               const float* __restrict__ fsin,
                                               unsigned short* __restrict__ Kc,
                                               unsigned short* __restrict__ Vc) {
  __shared__ unsigned short kt[64 * 72];  // rows padded to 72 shorts (144B, 16B-mult)
  __shared__ unsigned short vt[64 * 72];
  const int nt = blockIdx.x, bh = blockIdx.y;
  const int b = bh / Hc, h = bh % Hc;
  const int n0 = nt * 64;
  const int tid = threadIdx.x;
  const int nl = tid >> 3, slot = tid & 7;

#pragma unroll
  for (int it = 0; it < 2; ++it) {
    const int n = it * 32 + nl;
    const size_t base = (size_t)(b * Nc + n0 + n) * K3c + h * 64 + slot * 8;
    // V slice
    i32x4 vv = *(const i32x4*)&qkv[base + 2 * Cc];
    *(i32x4*)&vt[n * 72 + slot * 8] = vv;
    // K slice, rope applied (4 pair-words)
    i32x4 kv = *(const i32x4*)&qkv[base + Cc];
    const f32x4 cv = *(const f32x4*)&fcos[(n0 + n) * 32 + slot * 4];
    const f32x4 sv = *(const f32x4*)&fsin[(n0 + n) * 32 + slot * 4];
    i32x4 ko;
    ko.x = (int)rope_pair((unsigned int)kv.x, cv.x, sv.x);
    ko.y = (int)rope_pair((unsigned int)kv.y, cv.y, sv.y);
    ko.z = (int)rope_pair((unsigned int)kv.z, cv.z, sv.z);
    ko.w = (int)rope_pair((unsigned int)kv.w, cv.w, sv.w);
    *(i32x4*)&kt[n * 72 + slot * 8] = ko;
  }
  __syncthreads();

#pragma unroll
  for (int it = 0; it < 2; ++it) {
    const int task = it * 256 + tid;
    const int g = task >> 6;       // 0..7: Vc n-chunk / Kc d-chunk
    const int d = task & 63;       // 0..63: Vc d / Kc local n
    // Vc[g][d] <- V[n0+g*8+j][d]
    unsigned short tmpv[8];
#pragma unroll
    for (int j = 0; j < 8; ++j) tmpv[j] = vt[(g * 8 + j) * 72 + d];
    *(i32x4*)&Vc[(((size_t)bh * 256 + (n0 >> 3) + g) * 64 + d) * 8] = *(const i32x4*)tmpv;
    // Kc[ch=g][n0+d] <- K[n0+d][g*8 .. +8)
    *(i32x4*)&Kc[(((size_t)bh * 8 + g) * Nc + n0 + d) * 8] = *(const i32x4*)&kt[d * 72 + g * 8];
  }
}

// ---------------------------------------------------------------------------
// Causal flash attention — barrier-free / LDS-free; fragment math identical
// to round 5. Round-6 change: K/V loads go through the coalesced Kc/Vc
// layouts (lane-contiguous 512B runs instead of 32-line 128B-stride
// gathers). All 4 waves of a block read identical K/V bytes -> L1 reuse.
// ---------------------------------------------------------------------------
__global__ __launch_bounds__(256, 3) void attn_fwd(const unsigned short* __restrict__ Qp,
                                                   const unsigned short* __restrict__ Kcp,
                                                   const unsigned short* __restrict__ Vcp,
                                                   unsigned short* __restrict__ Op) {
  const int id = blockIdx.x;
  const int x8 = id & 7;
  const int r = id >> 3;
  const int qg = r / 6;
  const int bh = x8 + ((r % 6) << 3);
  const int q0 = (15 - qg) * 128;
  const int tid = threadIdx.x, w = tid >> 6, lane = tid & 63;
  const int qc = lane & 31, hi = lane >> 5;
  const int qw0 = q0 + w * 32;        // wave's first q-row
  const int qrow = qw0 + qc;          // this lane's q index
  const int qwmax = qw0 + 31;
  const unsigned short* Kcb = Kcp + (size_t)bh * (8 * Nc * 8);
  const unsigned short* Vcb = Vcp + (size_t)bh * (256 * 64 * 8);

  bf16x8 qf[4];
  {
    const unsigned short* qptr = Qp + ((size_t)bh * Nc + qrow) * 64 + hi * 8;
#pragma unroll
    for (int ks = 0; ks < 4; ++ks) qf[ks] = *(const bf16x8*)(qptr + ks * 16);
  }

  f32x16 oacc[2];
#pragma unroll
  for (int dt = 0; dt < 2; ++dt)
#pragma unroll
    for (int j = 0; j < 16; ++j) oacc[dt][j] = 0.f;
  float m_run = -1e30f, l_run = 0.f;

  for (int k0 = 0; k0 <= qwmax; k0 += 64) {
    // --- K fragments (coalesced: lanes qc contiguous 16B -> 512B runs)
    bf16x8 kf[2][4];
#pragma unroll
    for (int f = 0; f < 2; ++f)
#pragma unroll
      for (int ks = 0; ks < 4; ++ks)
        kf[f][ks] = *(const bf16x8*)&Kcb[(((2 * ks + hi) * Nc) + k0 + f * 32 + qc) * 8];

    // --- V fragments (coalesced), issued before QK^T so latency hides
    bf16x8 vf[2][4];
#pragma unroll
    for (int dt = 0; dt < 2; ++dt)
#pragma unroll
      for (int ks = 0; ks < 4; ++ks)
        vf[dt][ks] = *(const bf16x8*)&Vcb[(((k0 >> 3) + 2 * ks + hi) * 64 + dt * 32 + qc) * 8];

    // --- QK^T : S^T[kv][q] (already in exp2 domain; Q pre-scaled)
    f32x16 sacc[2];
#pragma unroll
    for (int f = 0; f < 2; ++f)
#pragma unroll
      for (int j = 0; j < 16; ++j) sacc[f][j] = 0.f;
#pragma unroll
    for (int f = 0; f < 2; ++f)
#pragma unroll
      for (int ks = 0; ks < 4; ++ks)
        sacc[f] = __builtin_amdgcn_mfma_f32_32x32x16_bf16(kf[f][ks], qf[ks], sacc[f], 0, 0, 0);

    // --- causal mask folded into sacc; lane kv row: f*32+(rr&3)+8*(rr>>2)+4*hi
    if (k0 + 63 > qw0) {
#pragma unroll
      for (int f = 0; f < 2; ++f)
#pragma unroll
        for (int rr = 0; rr < 16; ++rr) {
          const int kvi = k0 + f * 32 + (rr & 3) + ((rr >> 2) << 3) + (hi << 2);
          if (kvi > qrow) sacc[f][rr] = -1e30f;
        }
    }

    // --- online softmax: tree max
    float mx[16];
#pragma unroll
    for (int j = 0; j < 16; ++j) mx[j] = fmaxf(sacc[0][j], sacc[1][j]);
#pragma unroll
    for (int st = 8; st >= 1; st >>= 1)
#pragma unroll
      for (int j = 0; j < st; ++j) mx[j] = fmaxf(mx[j], mx[j + st]);
    const float pmax = fmaxf(mx[0], __shfl_xor(mx[0], 32, 64));

    if (!__all(pmax - m_run <= 11.5f)) {  // defer-max (T13)
      const float m_new = fmaxf(m_run, pmax);
      const float rs = EXP2(m_run - m_new);
      l_run *= rs;
#pragma unroll
      for (int dt = 0; dt < 2; ++dt)
#pragma unroll
        for (int j = 0; j < 16; ++j) oacc[dt][j] *= rs;
      m_run = m_new;
    }

    // --- P = exp2(S - m); masked entries underflow to 0
    float p[32];
#pragma unroll
    for (int f = 0; f < 2; ++f)
#pragma unroll
      for (int rr = 0; rr < 16; ++rr) p[f * 16 + rr] = EXP2(sacc[f][rr] - m_run);

    // tree sum
    float ts[16];
#pragma unroll
    for (int j = 0; j < 16; ++j) ts[j] = p[j] + p[16 + j];
#pragma unroll
    for (int st = 8; st >= 1; st >>= 1)
#pragma unroll
      for (int j = 0; j < st; ++j) ts[j] += ts[j + st];
    l_run += ts[0] + __shfl_xor(ts[0], 32, 64);

    unsigned int pw[2][8];
#pragma unroll
    for (int f = 0; f < 2; ++f) {
#pragma unroll
      for (int j = 0; j < 8; ++j)
        pw[f][j] = cvtpk_bf16(p[f * 16 + 2 * j], p[f * 16 + 2 * j + 1]);
      // T12: earlier-kv word is vdst (vdst[32:63] <-> vsrc[0:31])
      asm volatile("v_permlane32_swap_b32 %0, %1" : "+v"(pw[f][0]), "+v"(pw[f][2]));
      asm volatile("v_permlane32_swap_b32 %0, %1" : "+v"(pw[f][1]), "+v"(pw[f][3]));
      asm volatile("v_permlane32_swap_b32 %0, %1" : "+v"(pw[f][4]), "+v"(pw[f][6]));
      asm volatile("v_permlane32_swap_b32 %0, %1" : "+v"(pw[f][5]), "+v"(pw[f][7]));
    }

    // --- PV: O^T[d][q] += V^T x P
#pragma unroll
    for (int dt = 0; dt < 2; ++dt)
#pragma unroll
      for (int ks = 0; ks < 4; ++ks) {
        i32x4 pi;
        pi.x = (int)pw[ks >> 1][(ks & 1) * 4 + 0];
        pi.y = (int)pw[ks >> 1][(ks & 1) * 4 + 1];
        pi.z = (int)pw[ks >> 1][(ks & 1) * 4 + 2];
        pi.w = (int)pw[ks >> 1][(ks & 1) * 4 + 3];
        bf16x8 pf = __builtin_bit_cast(bf16x8, pi);
        oacc[dt] = __builtin_amdgcn_mfma_f32_32x32x16_bf16(vf[dt][ks], pf, oacc[dt], 0, 0, 0);
      }
  }

  // --- epilogue: lane owns q column; d = dt*32 + rq*8 + hi*4 + (0..3)
  const float inv = 1.f / l_run;
  const int b = bh / Hc, h = bh % Hc;
  unsigned short* orow = Op + ((size_t)(b * Nc + qrow)) * Cc + h * 64;
#pragma unroll
  for (int dt = 0; dt < 2; ++dt)
#pragma unroll
    for (int rq = 0; rq < 4; ++rq) {
      const float o0 = oacc[dt][rq * 4 + 0] * inv;
      const float o1 = oacc[dt][rq * 4 + 1] * inv;
      const float o2 = oacc[dt][rq * 4 + 2] * inv;
      const float o3 = oacc[dt][rq * 4 + 3] * inv;
      uint2 val;
      val.x = f2bf(o0) | (f2bf(o1) << 16);
      val.y = f2bf(o2) | (f2bf(o3) << 16);
      *(uint2*)(orow + dt * 32 + rq * 8 + hi * 4) = val;
    }
}

// ---------------------------------------------------------------------------
// Workspace layout (75,497,472 B total):
//   [0,       37.75M) qkv bf16          (later reused as attn output)
//   [37.75M, +12.58M) x_bf16, then Q    (x dead before rope_q writes Q)
//   [50.33M, +12.58M) wqkv_bf16, then Kc (wqkv dead before pack_kv)
//   [62.91M, +12.58M) Vc, then wproj_bf16 after attn consumes Vc
// ---------------------------------------------------------------------------
extern "C" void kernel_launch(void* const* d_in, const int* in_sizes, int n_in,
                              void* d_out, int out_size, void* d_ws, size_t ws_size,
                              hipStream_t stream) {
  const float* x = (const float*)d_in[0];
  const float* fcos = (const float*)d_in[1];
  const float* fsin = (const float*)d_in[2];
  // d_in[3] (mask) unused: causal structure applied analytically
  const float* wqkv = (const float*)d_in[4];
  const float* wproj = (const float*)d_in[5];
  const float* bproj = (const float*)d_in[6];

  char* ws = (char*)d_ws;
  unsigned short* qkvb = (unsigned short*)ws;
  unsigned short* Qb = (unsigned short*)(ws + 37748736);
  unsigned short* Kcb = (unsigned short*)(ws + 37748736 + 12582912);
  unsigned short* Vcb = (unsigned short*)(ws + 37748736 + 2 * 12582912);
  unsigned short* xb = Qb;
  unsigned short* wqkvb = Kcb;
  unsigned short* wprojb = Vcb;
  unsigned short* attnb = qkvb;

  // 0. fp32 -> bf16 converts
  cvt_f32_bf16<<<dim3(786432 / 256), 256, 0, stream>>>(x, xb, 786432);
  cvt_f32_bf16<<<dim3(221184 / 256), 256, 0, stream>>>(wqkv, wqkvb, 221184);
  // 1. qkv = x @ w_qkv^T (bf16 out)
  gemm_bt16<1><<<dim3(K3c / 128, Mc / 128), 256, 0, stream>>>(xb, wqkvb, qkvb, nullptr,
                                                              K3c, Cc);
  // 2. RoPE -> Q [B,H,N,Dh] (pre-scaled by KL)
  rope_q<<<dim3(Bc * Nc * Hc * 32 / 256), 256, 0, stream>>>(qkvb, fcos, fsin, Qb);
  // 3. K-rope + chunk-major packs -> Kc, Vc
  pack_kv<<<dim3(Nc / 64, Bc * Hc), 256, 0, stream>>>(qkvb, fcos, fsin, Kcb, Vcb);
  // 4. causal attention -> attnb [B,N,C] bf16 (768 blocks, XCD-pinned bh)
  attn_fwd<<<dim3(768), 256, 0, stream>>>(Qb, Kcb, Vcb, attnb);
  // 5. out = attn @ w_proj^T + b (fp32 out)
  cvt_f32_bf16<<<dim3(73728 / 256), 256, 0, stream>>>(wproj, wprojb, 73728);
  gemm_bt16<0><<<dim3(Cc / 128, Mc / 128), 256, 0, stream>>>(attnb, wprojb, d_out, bproj,
                                                             Cc, Cc);
}